// Round 1
// baseline (1567.966 us; speedup 1.0000x reference)
//
#include <hip/hip_runtime.h>
#include <hip/hip_bf16.h>

#define N_NODES 100000
// R16: src-range phased CSR. Edges are count-sorted by (dst, src/RNG) so each
// row's adjacency is grouped into NR=8 src ranges of 12500 nodes (3.2 MB bf16
// slab -> fits one 4 MB XCD L2). G_PART widened 16->128 so the (dst,range)
// bins (NPG*NR = 6256) still fit the same 25 KB LDS histogram.
#define G_PART 128
#define NPG 782            // ceil(N/G_PART)
#define NR 8               // src ranges
#define RNG 12500          // nodes per src range
#define BINS (NPG * NR)    // 6256 bins per dst group
#define BINS_PAD 6272
#define B_PART 12          // blocks per group; grid 1536 = 6 blocks/CU
#define A_BLOCKS 1024      // partition blocks
#define NBINS (N_NODES * NR)
#define NPB 64             // nodes per agg_gemm block (4 MFMA tiles)

// ---------------------------------------------------------------- CSR build
// R5: device atomics are memory-side -> LDS hist. R6: occupancy. R7: don't
// pollute L2 with the stream. R8: radix partition, edges read ~once.
// R12: ushort partials. R14 lesson: nt ONLY on the bkt stream.
__global__ __launch_bounds__(256) void partition_edges(
    const int* __restrict__ src, const int* __restrict__ dst, int E,
    int* __restrict__ bkt, unsigned int* __restrict__ gcur, int cap) {
    __shared__ int cnt[G_PART];
    __shared__ unsigned int base[G_PART];
    __shared__ unsigned int cur[G_PART];
    int tid = threadIdx.x;
    if (tid < G_PART) cnt[tid] = 0;
    __syncthreads();
    int per = (E + A_BLOCKS - 1) / A_BLOCKS;
    int beg = blockIdx.x * per;
    int end = min(beg + per, E);
    for (int i = beg + tid; i < end; i += 256) {
        int d = dst[i];
        atomicAdd(&cnt[d / NPG], 1);
    }
    __syncthreads();
    if (tid < G_PART) {
        base[tid] = atomicAdd(&gcur[tid], (unsigned int)cnt[tid]);
        cur[tid] = 0;
    }
    __syncthreads();
    for (int i = beg + tid; i < end; i += 256) {
        int d = dst[i];
        int s = src[i];
        int g = d / NPG;
        unsigned int p = base[g] + atomicAdd(&cur[g], 1u);
        bkt[(size_t)g * cap + p] = ((d - g * NPG) << 17) | s;
    }
}

__global__ __launch_bounds__(256) void count_hist(const int* __restrict__ bkt,
                                                  const unsigned int* __restrict__ gcur,
                                                  int cap,
                                                  unsigned short* __restrict__ partial) {
    __shared__ int hist[BINS_PAD];
    int g = blockIdx.x & (G_PART - 1);
    int b = blockIdx.x / G_PART;
    int tid = threadIdx.x;
    for (int i = tid; i < BINS; i += 256) hist[i] = 0;
    __syncthreads();
    int len = (int)gcur[g];
    int per = (len + B_PART - 1) / B_PART;
    int ibeg = b * per;
    int iend = min(ibeg + per, len);
    const int* bp = bkt + (size_t)g * cap;
    for (int i = ibeg + tid; i < iend; i += 256) {
        int v = __builtin_nontemporal_load(bp + i);
        int bin = (v >> 17) * NR + (v & 0x1FFFF) / RNG;   // (local_dst, src_range)
        atomicAdd(&hist[bin], 1);
    }
    __syncthreads();
    size_t basep = (size_t)(g * B_PART + b) * BINS;
    for (int j = tid; j < BINS; j += 256) partial[basep + j] = (unsigned short)hist[j];
}

__global__ __launch_bounds__(256) void scan_partials(unsigned short* __restrict__ partial,
                                                     int* __restrict__ cnt) {
    int B = blockIdx.x * 256 + threadIdx.x;   // global bin = node*NR + r
    if (B >= NBINS) return;
    int g = B / BINS;
    int i = B - g * BINS;
    size_t basep = (size_t)g * B_PART * BINS + i;
    int run = 0;
#pragma unroll 4
    for (int b = 0; b < B_PART; ++b) {
        size_t idx = basep + (size_t)b * BINS;
        int t = partial[idx];
        partial[idx] = (unsigned short)run;
        run += t;
    }
    cnt[B] = run;
}

// ---------------- grid-parallel exclusive scan over NBINS (4096 elems/block
// so the 2-level scan still fits: 196 block sums <= 256)
#define SCHUNK 4096

__global__ __launch_bounds__(256) void scan_blocks(const int* __restrict__ cnt,
                                                   int* __restrict__ boff,
                                                   int* __restrict__ block_sums, int n) {
    __shared__ int ts[256];
    int tid = threadIdx.x;
    int base = blockIdx.x * SCHUNK + tid * 16;
    int v[16];
    int s = 0;
#pragma unroll
    for (int j = 0; j < 16; ++j) {
        int i = base + j;
        v[j] = (i < n) ? cnt[i] : 0;
        s += v[j];
    }
    ts[tid] = s;
    __syncthreads();
    for (int off = 1; off < 256; off <<= 1) {
        int t = 0;
        if (tid >= off) t = ts[tid - off];
        __syncthreads();
        if (tid >= off) ts[tid] += t;
        __syncthreads();
    }
    int run = (tid > 0) ? ts[tid - 1] : 0;
    if (tid == 255) block_sums[blockIdx.x] = ts[255];
#pragma unroll
    for (int j = 0; j < 16; ++j) {
        int i = base + j;
        if (i < n) boff[i] = run;
        run += v[j];
    }
}

__global__ __launch_bounds__(256) void scan_sums(int* __restrict__ block_sums, int nb,
                                                 int* __restrict__ boff, int n) {
    __shared__ int ts[256];
    int tid = threadIdx.x;
    int v = (tid < nb) ? block_sums[tid] : 0;
    ts[tid] = v;
    __syncthreads();
    for (int off = 1; off < 256; off <<= 1) {
        int t = 0;
        if (tid >= off) t = ts[tid - off];
        __syncthreads();
        if (tid >= off) ts[tid] += t;
        __syncthreads();
    }
    if (tid < nb) block_sums[tid] = (tid > 0) ? ts[tid - 1] : 0;
    if (tid == 255) boff[n] = ts[255];
}

__global__ __launch_bounds__(256) void scan_add(int* __restrict__ boff,
                                                const int* __restrict__ block_sums, int n) {
    int tid = threadIdx.x;
    int off = block_sums[blockIdx.x];
    int base = blockIdx.x * SCHUNK + tid * 16;
#pragma unroll
    for (int j = 0; j < 16; ++j) {
        int i = base + j;
        if (i < n) boff[i] += off;
    }
}

__global__ __launch_bounds__(256) void fill_hist(const int* __restrict__ bkt,
                                                 const unsigned int* __restrict__ gcur,
                                                 int cap,
                                                 const unsigned short* __restrict__ partial,
                                                 const int* __restrict__ boff,
                                                 int* __restrict__ csr_src) {
    __shared__ int cur[BINS_PAD];
    int g = blockIdx.x & (G_PART - 1);
    int b = blockIdx.x / G_PART;
    int tid = threadIdx.x;
    size_t pbase = (size_t)(g * B_PART + b) * BINS;
    int gb = g * BINS;
    for (int i = tid; i < BINS; i += 256) {
        int node = g * NPG + (i >> 3);
        if (node < N_NODES) cur[i] = boff[gb + i] + (int)partial[pbase + i];
    }
    __syncthreads();
    int len = (int)gcur[g];
    int per = (len + B_PART - 1) / B_PART;
    int ibeg = b * per;
    int iend = min(ibeg + per, len);
    const int* bp = bkt + (size_t)g * cap;
    for (int i = ibeg + tid; i < iend; i += 256) {
        int v = __builtin_nontemporal_load(bp + i);
        int bin = (v >> 17) * NR + (v & 0x1FFFF) / RNG;
        int p = atomicAdd(&cur[bin], 1);
        csr_src[p] = v & 0x1FFFF;
    }
}

// ---------------------------------------------------------------- bf16 packs
__global__ __launch_bounds__(256) void pack_bf16(const float* __restrict__ in,
                                                 uint2* __restrict__ out, int n4) {
    int i = blockIdx.x * 256 + threadIdx.x;
    if (i >= n4) return;
    float4 v = *(const float4*)&in[(size_t)i * 4];
    __hip_bfloat162 p0 = __float22bfloat162_rn(make_float2(v.x, v.y));
    __hip_bfloat162 p1 = __float22bfloat162_rn(make_float2(v.z, v.w));
    uint2 o;
    o.x = *(const uint*)&p0;
    o.y = *(const uint*)&p1;
    out[i] = o;
}

static __device__ inline unsigned short f2bf(float v) {
    __hip_bfloat16 b = __float2bfloat16(v);
    return *(const unsigned short*)&b;
}

__global__ __launch_bounds__(256) void pack_weights(
    const float* __restrict__ Wl1, const float* __restrict__ Wr1,
    const float* __restrict__ Wl2, const float* __restrict__ Wr2,
    const float* __restrict__ Wl3, const float* __restrict__ Wr3,
    unsigned short* __restrict__ Wc1, unsigned short* __restrict__ Wc2,
    unsigned short* __restrict__ W3c) {
    int idx = blockIdx.x * 256 + threadIdx.x;
    if (idx < 32768) {
        int n = idx >> 8, k = idx & 255;
        Wc1[idx] = f2bf((k < 128) ? Wl1[n * 128 + k] : Wr1[n * 128 + (k - 128)]);
    } else if (idx < 65536) {
        int t = idx - 32768;
        int n = t >> 8, k = t & 255;
        Wc2[t] = f2bf((k < 128) ? Wl2[n * 128 + k] : Wr2[n * 128 + (k - 128)]);
    } else if (idx < 65536 + 2048) {
        int t = idx - 65536;
        int n = t >> 7, k = t & 127;
        float v = (n < 6) ? Wl3[n * 128 + k] : ((n < 12) ? Wr3[(n - 6) * 128 + k] : 0.f);
        W3c[t] = f2bf(v);
    }
}

// --------------------------------------------- fused agg + MFMA GEMM (+lin3)
// R13: gather mean-agg rows into LDS, then MFMA tile. R15: prefetch self
// A-frags + bias, LDS-staged coalesced epilogue. csr loads PLAIN cached (R14).
// R16: persistent-ish blocks (64 nodes, grid 1563 ~= all resident at 6/CU)
// sweep NR=8 src ranges outermost; accumulators live in registers (32 VGPR)
// so the active 3.2 MB featb slab stays L2-resident per XCD across the
// whole sweep. No cross-block sync: alignment is loose but self-correcting
// (blocks running ahead miss and slow down).
typedef __attribute__((ext_vector_type(8))) short bfrag8;
typedef __attribute__((ext_vector_type(4))) float f32x4;

static __device__ inline float2 unpack2(uint v) {
    float2 r;
    r.x = __uint_as_float(v << 16);
    r.y = __uint_as_float(v & 0xffff0000u);
    return r;
}

__global__ __launch_bounds__(256, 6) void agg_gemm(
    const uint* __restrict__ featb,           // [N][64] bf16x2 gather table
    const unsigned short* __restrict__ Aself, // [M][128] bf16 self rows
    const int* __restrict__ boff,             // [N*NR+1] range-split row offsets
    const int* __restrict__ csr,
    const unsigned short* __restrict__ Wc,    // [128][256] bf16
    const float* __restrict__ bias,           // [128]
    unsigned short* __restrict__ outb,        // [M][128] bf16 (nullable)
    int do_lin3,
    const unsigned short* __restrict__ W3c,   // [16][128] bf16
    const float* __restrict__ b3,             // [6]
    unsigned short* __restrict__ zg,          // [M][8] bf16
    float* __restrict__ zs,                   // [M][6] fp32
    int M, int relu) {
    __shared__ unsigned short aggT[16][136];  // +8 pad
    __shared__ unsigned short h2T[16][136];
    int tid = threadIdx.x;
    int wave = tid >> 6;
    int lane = tid & 63;
    int mrow = lane & 15;
    int quad = lane >> 4;
    int base = blockIdx.x * NPB;

    // per-wave accumulators: 16 nodes (4 per tile x 4 tiles), statically indexed
    float accx[16], accy[16];
#pragma unroll
    for (int k = 0; k < 16; ++k) { accx[k] = 0.f; accy[k] = 0.f; }

    // ---- phase 1: src-range-phased gather
    for (int r = 0; r < NR; ++r) {
#pragma unroll
        for (int k = 0; k < 16; ++k) {
            int node = base + (k >> 2) * 16 + wave * 4 + (k & 3);
            if (node < M) {
                const int* bo = boff + node * NR + r;
                int beg = bo[0], end = bo[1];
                float sx = accx[k], sy = accy[k];
                int i = beg;
                for (; i + 4 <= end; i += 4) {
                    int s0 = csr[i], s1 = csr[i + 1], s2 = csr[i + 2], s3 = csr[i + 3];
                    uint v0 = featb[(size_t)s0 * 64 + lane];
                    uint v1 = featb[(size_t)s1 * 64 + lane];
                    uint v2 = featb[(size_t)s2 * 64 + lane];
                    uint v3 = featb[(size_t)s3 * 64 + lane];
                    float2 f0 = unpack2(v0), f1 = unpack2(v1);
                    float2 f2 = unpack2(v2), f3 = unpack2(v3);
                    sx += f0.x + f1.x + f2.x + f3.x;
                    sy += f0.y + f1.y + f2.y + f3.y;
                }
                for (; i < end; ++i) {
                    uint v = featb[(size_t)csr[i] * 64 + lane];
                    float2 f = unpack2(v);
                    sx += f.x;
                    sy += f.y;
                }
                accx[k] = sx;
                accy[k] = sy;
            }
        }
    }

    int t0 = wave * 2, t1 = wave * 2 + 1;
    float bc0 = bias[t0 * 16 + mrow];
    float bc1 = bias[t1 * 16 + mrow];

    // ---- phase 2: per-tile MFMA (4 tiles of 16 nodes)
#pragma unroll
    for (int t = 0; t < 4; ++t) {
        int tile = base + t * 16;
#pragma unroll
        for (int sub = 0; sub < 4; ++sub) {
            int node = tile + wave * 4 + sub;
            float inv = 0.f;
            if (node < M) {
                int b0 = boff[node * NR], e0 = boff[node * NR + NR];
                inv = (e0 > b0) ? 1.0f / (float)(e0 - b0) : 0.f;
            }
            __hip_bfloat162 p = __float22bfloat162_rn(
                make_float2(accx[t * 4 + sub] * inv, accy[t * 4 + sub] * inv));
            *(uint*)&aggT[wave * 4 + sub][lane * 2] = *(const uint*)&p;
        }
        int row = tile + mrow;
        int rc = (row < M) ? row : 0;
        const unsigned short* arow = Aself + (size_t)rc * 128;
        bfrag8 aself[4];  // issued before the barrier -> in flight during sync
#pragma unroll
        for (int ks = 0; ks < 4; ++ks)
            aself[ks] = *(const bfrag8*)(arow + ks * 32 + quad * 8);
        __syncthreads();
        f32x4 acc0 = (f32x4){0.f, 0.f, 0.f, 0.f};
        f32x4 acc1 = (f32x4){0.f, 0.f, 0.f, 0.f};
#pragma unroll
        for (int ks = 0; ks < 8; ++ks) {
            bfrag8 af;
            if (ks < 4) af = *(const bfrag8*)&aggT[mrow][ks * 32 + quad * 8];
            else af = aself[ks - 4];
            bfrag8 bf0 = *(const bfrag8*)(Wc + (size_t)(t0 * 16 + mrow) * 256 + ks * 32 + quad * 8);
            bfrag8 bf1 = *(const bfrag8*)(Wc + (size_t)(t1 * 16 + mrow) * 256 + ks * 32 + quad * 8);
            acc0 = __builtin_amdgcn_mfma_f32_16x16x32_bf16(af, bf0, acc0, 0, 0, 0);
            acc1 = __builtin_amdgcn_mfma_f32_16x16x32_bf16(af, bf1, acc1, 0, 0, 0);
        }
        // epilogue: stage C tile in LDS (col within tile = mrow, row = quad*4+rr)
#pragma unroll
        for (int tt = 0; tt < 2; ++tt) {
            f32x4 a = tt ? acc1 : acc0;
            int col = (wave * 2 + tt) * 16 + mrow;
            float bc = tt ? bc1 : bc0;
#pragma unroll
            for (int rr = 0; rr < 4; ++rr) {
                float v = a[rr] + bc;
                if (relu) v = fmaxf(v, 0.f);
                h2T[quad * 4 + rr][col] = f2bf(v);
            }
        }
        __syncthreads();
        // cooperative coalesced dump: 16 rows x 128 ushort, uint4 per thread
        if (outb) {
            int rr = tid >> 4;
            int c8 = (tid & 15) * 8;
            int orow = tile + rr;
            if (orow < M)
                *(uint4*)&outb[(size_t)orow * 128 + c8] = *(const uint4*)&h2T[rr][c8];
        }
        // fused lin3 (layer 2 only): one 16x16 tile, K=128, from h2T
        if (do_lin3 && wave == 0) {
            f32x4 acc = (f32x4){0.f, 0.f, 0.f, 0.f};
#pragma unroll
            for (int ks = 0; ks < 4; ++ks) {
                bfrag8 af = *(const bfrag8*)&h2T[mrow][ks * 32 + quad * 8];
                bfrag8 bf = *(const bfrag8*)(W3c + (size_t)mrow * 128 + ks * 32 + quad * 8);
                acc = __builtin_amdgcn_mfma_f32_16x16x32_bf16(af, bf, acc, 0, 0, 0);
            }
            int col = mrow;
#pragma unroll
            for (int rr = 0; rr < 4; ++rr) {
                int orow = tile + quad * 4 + rr;
                if (orow < M) {
                    float v = acc[rr];
                    if (col < 6) {
                        zg[(size_t)orow * 8 + col] = f2bf(v);
                    } else if (col < 12) {
                        zs[(size_t)orow * 6 + (col - 6)] = v + b3[col - 6];
                    }
                }
            }
        }
        __syncthreads();
    }
}

// ------------------------------------------- final: out[n][j] = mean_s zg[s][j] + zs[n][j]
__global__ void out_kernel(const unsigned short* __restrict__ zg,
                           const float* __restrict__ zs,
                           const int* __restrict__ boff,
                           const int* __restrict__ csr,
                           float* __restrict__ out, int M) {
    int idx = blockIdx.x * blockDim.x + threadIdx.x;
    int node = idx >> 3;
    int j = idx & 7;
    if (node >= M || j >= 6) return;
    int beg = boff[node * NR], end = boff[node * NR + NR];
    float acc = 0.f;
    int i = beg;
    for (; i + 4 <= end; i += 4) {
        int s0 = csr[i], s1 = csr[i + 1], s2 = csr[i + 2], s3 = csr[i + 3];
        uint z0 = zg[(size_t)s0 * 8 + j];
        uint z1 = zg[(size_t)s1 * 8 + j];
        uint z2 = zg[(size_t)s2 * 8 + j];
        uint z3 = zg[(size_t)s3 * 8 + j];
        acc += __uint_as_float(z0 << 16) + __uint_as_float(z1 << 16) +
               __uint_as_float(z2 << 16) + __uint_as_float(z3 << 16);
    }
    for (; i < end; ++i) {
        uint z = zg[(size_t)csr[i] * 8 + j];
        acc += __uint_as_float(z << 16);
    }
    float inv = (end > beg) ? 1.0f / (float)(end - beg) : 0.0f;
    out[(size_t)node * 6 + j] = acc * inv + zs[(size_t)node * 6 + j];
}

// ---------------------------------------------------------------- launch
static inline size_t align_up(size_t x, size_t a) { return (x + a - 1) & ~(a - 1); }

extern "C" void kernel_launch(void* const* d_in, const int* in_sizes, int n_in,
                              void* d_out, int out_size, void* d_ws, size_t ws_size,
                              hipStream_t stream) {
    const float* x = (const float*)d_in[0];
    const int* ei = (const int*)d_in[1];
    const float* Wl1 = (const float*)d_in[2];
    const float* Wr1 = (const float*)d_in[3];
    const float* b1 = (const float*)d_in[4];
    const float* Wl2 = (const float*)d_in[5];
    const float* Wr2 = (const float*)d_in[6];
    const float* b2 = (const float*)d_in[7];
    const float* Wl3 = (const float*)d_in[8];
    const float* Wr3 = (const float*)d_in[9];
    const float* b3 = (const float*)d_in[10];

    const int N = in_sizes[0] / 128;   // 100000
    const int E = in_sizes[1] / 2;     // 3200000
    const int* src = ei;
    const int* dst = ei + E;

    // workspace layout
    char* ws = (char*)d_ws;
    size_t off = 0;
    int* cnt = (int*)(ws + off);        off = align_up(off + (size_t)NBINS * 4, 512);
    int* boff = (int*)(ws + off);       off = align_up(off + (size_t)(NBINS + 1) * 4, 512);
    int* block_sums = (int*)(ws + off); off = align_up(off + 512 * 4, 512);
    unsigned int* gcur = (unsigned int*)(ws + off); off = align_up(off + G_PART * 4, 512);
    unsigned short* Wc1 = (unsigned short*)(ws + off); off = align_up(off + 128 * 256 * 2, 512);
    unsigned short* Wc2 = (unsigned short*)(ws + off); off = align_up(off + 128 * 256 * 2, 512);
    unsigned short* W3c = (unsigned short*)(ws + off); off = align_up(off + 16 * 128 * 2, 512);
    int* csr_src = (int*)(ws + off);    off = align_up(off + (size_t)E * 4, 512);
    float* slotA = (float*)(ws + off);  off = align_up(off + (size_t)N * 128 * 4, 512);
    float* slotB = (float*)(ws + off);  off = align_up(off + (size_t)N * 128 * 4, 512);
    uint2* h1b = (uint2*)(ws + off);    off = align_up(off + (size_t)N * 128 * 2, 512);
    // aliases (lifetimes disjoint):
    //  slotA: partial ushort [count..fill] (19.2MB); xb [pack..agg_gemm1] (25.6MB)
    //  slotB: bkt [partition..fill] (14.3MB); zg+zs [agg_gemm2..out] (4MB)
    unsigned short* partial = (unsigned short*)slotA;
    const int cap = 28000;  // per-bucket mean 25000, std ~157
    int* bkt = (int*)slotB;
    uint2* xb = (uint2*)slotA;          // written after fill (partial dead)
    unsigned short* zg = (unsigned short*)slotB;
    float* zs = (float*)((char*)slotB + align_up((size_t)N * 8 * 2, 512));
    (void)ws_size;

    // --- CSR build: radix partition + LDS histogram with (dst, src_range) key
    const int build_grid = G_PART * B_PART;          // 1536 = 6 blocks/CU

    hipMemsetAsync(gcur, 0, G_PART * 4, stream);
    partition_edges<<<A_BLOCKS, 256, 0, stream>>>(src, dst, E, bkt, gcur, cap);
    count_hist<<<build_grid, 256, 0, stream>>>(bkt, gcur, cap, partial);
    scan_partials<<<(NBINS + 255) / 256, 256, 0, stream>>>(partial, cnt);

    const int nscan = (NBINS + SCHUNK - 1) / SCHUNK;  // 196 <= 256
    scan_blocks<<<nscan, 256, 0, stream>>>(cnt, boff, block_sums, NBINS);
    scan_sums<<<1, 256, 0, stream>>>(block_sums, nscan, boff, NBINS);
    scan_add<<<nscan, 256, 0, stream>>>(boff, block_sums, NBINS);

    fill_hist<<<build_grid, 256, 0, stream>>>(bkt, gcur, cap, partial, boff, csr_src);

    // packs (xb after fill: partial slot is free)
    const int n4 = N * 32;
    pack_bf16<<<(n4 + 255) / 256, 256, 0, stream>>>(x, xb, n4);
    pack_weights<<<(65536 + 2048 + 255) / 256, 256, 0, stream>>>(
        Wl1, Wr1, Wl2, Wr2, Wl3, Wr3, Wc1, Wc2, W3c);

    const int aggGrid = (N + NPB - 1) / NPB;   // 1563 (~all resident at 6/CU)

    // layer 1: fused gather+GEMM -> h1b (bf16)
    agg_gemm<<<aggGrid, 256, 0, stream>>>(
        (const uint*)xb, (const unsigned short*)xb, boff, csr_src, Wc1, b1,
        (unsigned short*)h1b, 0, nullptr, nullptr, nullptr, nullptr, N, 1);
    // layer 2: fused gather+GEMM+lin3 -> zg (bf16) + zs (fp32); h2 never stored
    agg_gemm<<<aggGrid, 256, 0, stream>>>(
        (const uint*)h1b, (const unsigned short*)h1b, boff, csr_src, Wc2, b2,
        nullptr, 1, W3c, b3, zg, zs, N, 1);
    // final
    out_kernel<<<(N * 8 + 255) / 256, 256, 0, stream>>>(zg, zs, boff, csr_src,
                                                        (float*)d_out, N);
}

// Round 2
// 1123.097 us; speedup vs baseline: 1.3961x; 1.3961x over previous
//
#include <hip/hip_runtime.h>
#include <hip/hip_fp16.h>

#define N_NODES 100000
// R17: src-range phased gather, retry of R16 with the spill structurally
// removed. Accumulators are 16 NAMED __half2 regs per wave (packed f16
// accumulation, v_pk_add_f16) -- no arrays, no runtime indexing (rule #20;
// R16's 530MB WRITE_SIZE was scratch spill of accx[16]/accy[16]).
// CSR is RANGE-MAJOR (bin = r*N + dst) so each (block,range) step reads a
// contiguous ~1KB csr run -- csr L2 footprint ~0.2MB, can't evict the
// 3.2MB feature slab. Whole pipeline moves bf16 -> f16 (table, weights,
// MFMA) -- f16 has 10 mantissa bits vs bf16's 7, strictly better here.
#define G_PART 128
#define NPG 782            // ceil(N/G_PART)
#define NR 8               // src ranges
#define RNG 12500          // nodes per src range (3.2MB f16 slab < 4MB XCD L2)
#define BINS (NPG * NR)    // 6256 bins per dst group
#define BINS_PAD 6272
#define B_PART 12          // blocks per group; grid 1536 = 6 blocks/CU
#define A_BLOCKS 1024
#define NBINS (N_NODES * NR)
#define NPB 64             // nodes per agg_gemm block; grid 1563 ~ all-resident

// ---------------------------------------------------------------- CSR build
__global__ __launch_bounds__(256) void partition_edges(
    const int* __restrict__ src, const int* __restrict__ dst, int E,
    int* __restrict__ bkt, unsigned int* __restrict__ gcur, int cap) {
    __shared__ int cnt[G_PART];
    __shared__ unsigned int base[G_PART];
    __shared__ unsigned int cur[G_PART];
    int tid = threadIdx.x;
    if (tid < G_PART) cnt[tid] = 0;
    __syncthreads();
    int per = (E + A_BLOCKS - 1) / A_BLOCKS;
    int beg = blockIdx.x * per;
    int end = min(beg + per, E);
    for (int i = beg + tid; i < end; i += 256) {
        int d = dst[i];
        atomicAdd(&cnt[d / NPG], 1);
    }
    __syncthreads();
    if (tid < G_PART) {
        base[tid] = atomicAdd(&gcur[tid], (unsigned int)cnt[tid]);
        cur[tid] = 0;
    }
    __syncthreads();
    for (int i = beg + tid; i < end; i += 256) {
        int d = dst[i];
        int s = src[i];
        int g = d / NPG;
        unsigned int p = base[g] + atomicAdd(&cur[g], 1u);
        bkt[(size_t)g * cap + p] = ((d - g * NPG) << 17) | s;
    }
}

__global__ __launch_bounds__(256) void count_hist(const int* __restrict__ bkt,
                                                  const unsigned int* __restrict__ gcur,
                                                  int cap,
                                                  unsigned short* __restrict__ partial) {
    __shared__ int hist[BINS_PAD];
    int g = blockIdx.x & (G_PART - 1);
    int b = blockIdx.x / G_PART;
    int tid = threadIdx.x;
    for (int i = tid; i < BINS; i += 256) hist[i] = 0;
    __syncthreads();
    int len = (int)gcur[g];
    int per = (len + B_PART - 1) / B_PART;
    int ibeg = b * per;
    int iend = min(ibeg + per, len);
    const int* bp = bkt + (size_t)g * cap;
    for (int i = ibeg + tid; i < iend; i += 256) {
        int v = __builtin_nontemporal_load(bp + i);
        int bin = ((v & 0x1FFFF) / RNG) * NPG + (v >> 17);  // (src_range, local_dst)
        atomicAdd(&hist[bin], 1);
    }
    __syncthreads();
    size_t basep = (size_t)(g * B_PART + b) * BINS;
    for (int j = tid; j < BINS; j += 256) partial[basep + j] = (unsigned short)hist[j];
}

// global bin order is RANGE-MAJOR: B = r*N + dst  (csr becomes range-major)
__global__ __launch_bounds__(256) void scan_partials(unsigned short* __restrict__ partial,
                                                     int* __restrict__ cnt) {
    int B = blockIdx.x * 256 + threadIdx.x;
    if (B >= NBINS) return;
    int r = B / N_NODES;
    int dstn = B - r * N_NODES;
    int g = dstn / NPG;
    int i = r * NPG + (dstn - g * NPG);
    size_t basep = (size_t)g * B_PART * BINS + i;
    int run = 0;
#pragma unroll 4
    for (int b = 0; b < B_PART; ++b) {
        size_t idx = basep + (size_t)b * BINS;
        int t = partial[idx];
        partial[idx] = (unsigned short)run;
        run += t;
    }
    cnt[B] = run;
}

__global__ __launch_bounds__(256) void deg_kernel(const int* __restrict__ cnt,
                                                  int* __restrict__ deg) {
    int n = blockIdx.x * 256 + threadIdx.x;
    if (n >= N_NODES) return;
    int s = 0;
#pragma unroll
    for (int r = 0; r < NR; ++r) s += cnt[(size_t)r * N_NODES + n];
    deg[n] = s;
}

// ---------------- grid-parallel exclusive scan over NBINS
#define SCHUNK 4096

__global__ __launch_bounds__(256) void scan_blocks(const int* __restrict__ cnt,
                                                   int* __restrict__ boff,
                                                   int* __restrict__ block_sums, int n) {
    __shared__ int ts[256];
    int tid = threadIdx.x;
    int base = blockIdx.x * SCHUNK + tid * 16;
    int v[16];
    int s = 0;
#pragma unroll
    for (int j = 0; j < 16; ++j) {
        int i = base + j;
        v[j] = (i < n) ? cnt[i] : 0;
        s += v[j];
    }
    ts[tid] = s;
    __syncthreads();
    for (int off = 1; off < 256; off <<= 1) {
        int t = 0;
        if (tid >= off) t = ts[tid - off];
        __syncthreads();
        if (tid >= off) ts[tid] += t;
        __syncthreads();
    }
    int run = (tid > 0) ? ts[tid - 1] : 0;
    if (tid == 255) block_sums[blockIdx.x] = ts[255];
#pragma unroll
    for (int j = 0; j < 16; ++j) {
        int i = base + j;
        if (i < n) boff[i] = run;
        run += v[j];
    }
}

__global__ __launch_bounds__(256) void scan_sums(int* __restrict__ block_sums, int nb,
                                                 int* __restrict__ boff, int n) {
    __shared__ int ts[256];
    int tid = threadIdx.x;
    int v = (tid < nb) ? block_sums[tid] : 0;
    ts[tid] = v;
    __syncthreads();
    for (int off = 1; off < 256; off <<= 1) {
        int t = 0;
        if (tid >= off) t = ts[tid - off];
        __syncthreads();
        if (tid >= off) ts[tid] += t;
        __syncthreads();
    }
    if (tid < nb) block_sums[tid] = (tid > 0) ? ts[tid - 1] : 0;
    if (tid == 255) boff[n] = ts[255];
}

__global__ __launch_bounds__(256) void scan_add(int* __restrict__ boff,
                                                const int* __restrict__ block_sums, int n) {
    int tid = threadIdx.x;
    int off = block_sums[blockIdx.x];
    int base = blockIdx.x * SCHUNK + tid * 16;
#pragma unroll
    for (int j = 0; j < 16; ++j) {
        int i = base + j;
        if (i < n) boff[i] += off;
    }
}

__global__ __launch_bounds__(256) void fill_hist(const int* __restrict__ bkt,
                                                 const unsigned int* __restrict__ gcur,
                                                 int cap,
                                                 const unsigned short* __restrict__ partial,
                                                 const int* __restrict__ boff,
                                                 int* __restrict__ csr_src) {
    __shared__ int cur[BINS_PAD];
    int g = blockIdx.x & (G_PART - 1);
    int b = blockIdx.x / G_PART;
    int tid = threadIdx.x;
    size_t pbase = (size_t)(g * B_PART + b) * BINS;
    for (int i = tid; i < BINS; i += 256) {
        int r = i / NPG;
        int dstn = g * NPG + (i - r * NPG);
        if (dstn < N_NODES)
            cur[i] = boff[(size_t)r * N_NODES + dstn] + (int)partial[pbase + i];
    }
    __syncthreads();
    int len = (int)gcur[g];
    int per = (len + B_PART - 1) / B_PART;
    int ibeg = b * per;
    int iend = min(ibeg + per, len);
    const int* bp = bkt + (size_t)g * cap;
    for (int i = ibeg + tid; i < iend; i += 256) {
        int v = __builtin_nontemporal_load(bp + i);
        int bin = ((v & 0x1FFFF) / RNG) * NPG + (v >> 17);
        int p = atomicAdd(&cur[bin], 1);
        csr_src[p] = v & 0x1FFFF;
    }
}

// ---------------------------------------------------------------- f16 packs
__global__ __launch_bounds__(256) void pack_f16(const float* __restrict__ in,
                                                uint2* __restrict__ out, int n4) {
    int i = blockIdx.x * 256 + threadIdx.x;
    if (i >= n4) return;
    float4 v = *(const float4*)&in[(size_t)i * 4];
    __half2 p0 = __floats2half2_rn(v.x, v.y);
    __half2 p1 = __floats2half2_rn(v.z, v.w);
    uint2 o;
    o.x = *(const uint*)&p0;
    o.y = *(const uint*)&p1;
    out[i] = o;
}

static __device__ inline unsigned short f2h(float v) {
    __half h = __float2half(v);
    return *(const unsigned short*)&h;
}

__global__ __launch_bounds__(256) void pack_weights(
    const float* __restrict__ Wl1, const float* __restrict__ Wr1,
    const float* __restrict__ Wl2, const float* __restrict__ Wr2,
    const float* __restrict__ Wl3, const float* __restrict__ Wr3,
    unsigned short* __restrict__ Wc1, unsigned short* __restrict__ Wc2,
    unsigned short* __restrict__ W3c) {
    int idx = blockIdx.x * 256 + threadIdx.x;
    if (idx < 32768) {
        int n = idx >> 8, k = idx & 255;
        Wc1[idx] = f2h((k < 128) ? Wl1[n * 128 + k] : Wr1[n * 128 + (k - 128)]);
    } else if (idx < 65536) {
        int t = idx - 32768;
        int n = t >> 8, k = t & 255;
        Wc2[t] = f2h((k < 128) ? Wl2[n * 128 + k] : Wr2[n * 128 + (k - 128)]);
    } else if (idx < 65536 + 2048) {
        int t = idx - 65536;
        int n = t >> 7, k = t & 127;
        float v = (n < 6) ? Wl3[n * 128 + k] : ((n < 12) ? Wr3[(n - 6) * 128 + k] : 0.f);
        W3c[t] = f2h(v);
    }
}

// --------------------------------------------- fused agg + MFMA GEMM (+lin3)
typedef __attribute__((ext_vector_type(8))) _Float16 hfrag8;
typedef __attribute__((ext_vector_type(4))) float f32x4;

// gather one (node, range) segment into a NAMED __half2 accumulator
#define GATH(ACC, T, S) do {                                                  \
    int node_ = base + (T)*16 + w4 + (S);                                     \
    if (node_ < M) {                                                          \
        int beg_ = bo[node_], end_ = bo[node_ + 1];                           \
        int i_ = beg_;                                                        \
        for (; i_ + 4 <= end_; i_ += 4) {                                     \
            int s0_ = csr[i_], s1_ = csr[i_ + 1];                             \
            int s2_ = csr[i_ + 2], s3_ = csr[i_ + 3];                         \
            __half2 v0_ = featb[(uint)s0_ * 64u + lane];                      \
            __half2 v1_ = featb[(uint)s1_ * 64u + lane];                      \
            __half2 v2_ = featb[(uint)s2_ * 64u + lane];                      \
            __half2 v3_ = featb[(uint)s3_ * 64u + lane];                      \
            ACC = __hadd2(ACC, __hadd2(__hadd2(v0_, v1_), __hadd2(v2_, v3_)));\
        }                                                                     \
        for (; i_ < end_; ++i_)                                               \
            ACC = __hadd2(ACC, featb[(uint)csr[i_] * 64u + lane]);            \
    }                                                                         \
} while (0)

#define STAGE1(ACC, T, S) do {                                                \
    int node_ = base + (T)*16 + w4 + (S);                                     \
    float iv_ = 0.f;                                                          \
    if (node_ < M) {                                                          \
        int dg_ = deg[node_];                                                 \
        iv_ = (dg_ > 0) ? 1.0f / (float)dg_ : 0.f;                            \
    }                                                                         \
    float2 f_ = __half22float2(ACC);                                          \
    aggT[w4 + (S)][lane] = __floats2half2_rn(f_.x * iv_, f_.y * iv_);         \
} while (0)

#define TILE_BODY(T, A0, A1, A2, A3) do {                                     \
    int tile_ = base + (T)*16;                                                \
    STAGE1(A0, T, 0); STAGE1(A1, T, 1); STAGE1(A2, T, 2); STAGE1(A3, T, 3);   \
    int row_ = tile_ + mrow;                                                  \
    int rc_ = (row_ < M) ? row_ : 0;                                          \
    const _Float16* arow_ = Aself + (size_t)rc_ * 128;                        \
    hfrag8 as0_ = *(const hfrag8*)(arow_ + 0 * 32 + quad * 8);                \
    hfrag8 as1_ = *(const hfrag8*)(arow_ + 1 * 32 + quad * 8);                \
    hfrag8 as2_ = *(const hfrag8*)(arow_ + 2 * 32 + quad * 8);                \
    hfrag8 as3_ = *(const hfrag8*)(arow_ + 3 * 32 + quad * 8);                \
    __syncthreads();                                                          \
    f32x4 acc0_ = (f32x4){0.f, 0.f, 0.f, 0.f};                                \
    f32x4 acc1_ = (f32x4){0.f, 0.f, 0.f, 0.f};                                \
    _Pragma("unroll")                                                         \
    for (int ks = 0; ks < 8; ++ks) {                                          \
        hfrag8 af_;                                                           \
        if (ks < 4) af_ = *(const hfrag8*)&aggT[mrow][ks * 16 + quad * 4];    \
        else af_ = (ks == 4) ? as0_ : ((ks == 5) ? as1_ : ((ks == 6) ? as2_ : as3_)); \
        hfrag8 bf0_ = *(const hfrag8*)(Wc + (size_t)(t0 * 16 + mrow) * 256 + ks * 32 + quad * 8); \
        hfrag8 bf1_ = *(const hfrag8*)(Wc + (size_t)(t1 * 16 + mrow) * 256 + ks * 32 + quad * 8); \
        acc0_ = __builtin_amdgcn_mfma_f32_16x16x32_f16(af_, bf0_, acc0_, 0, 0, 0); \
        acc1_ = __builtin_amdgcn_mfma_f32_16x16x32_f16(af_, bf1_, acc1_, 0, 0, 0); \
    }                                                                         \
    _Pragma("unroll")                                                         \
    for (int tt = 0; tt < 2; ++tt) {                                          \
        f32x4 a_ = tt ? acc1_ : acc0_;                                        \
        int col_ = (wave * 2 + tt) * 16 + mrow;                               \
        float bc_ = tt ? bc1 : bc0;                                           \
        _Pragma("unroll")                                                     \
        for (int rr = 0; rr < 4; ++rr) {                                      \
            float v_ = a_[rr] + bc_;                                          \
            if (relu) v_ = fmaxf(v_, 0.f);                                    \
            h2T[quad * 4 + rr][col_] = f2h(v_);                               \
        }                                                                     \
    }                                                                         \
    __syncthreads();                                                          \
    if (outb) {                                                               \
        int rr_ = tid >> 4;                                                   \
        int c8_ = (tid & 15) * 8;                                             \
        int orow_ = tile_ + rr_;                                              \
        if (orow_ < M)                                                        \
            *(uint4*)&outb[(size_t)orow_ * 128 + c8_] = *(const uint4*)&h2T[rr_][c8_]; \
    }                                                                         \
    if (do_lin3 && wave == 0) {                                               \
        f32x4 acc_ = (f32x4){0.f, 0.f, 0.f, 0.f};                             \
        _Pragma("unroll")                                                     \
        for (int ks = 0; ks < 4; ++ks) {                                      \
            hfrag8 af_ = *(const hfrag8*)&h2T[mrow][ks * 32 + quad * 8];      \
            hfrag8 bf_ = *(const hfrag8*)(W3c + (size_t)mrow * 128 + ks * 32 + quad * 8); \
            acc_ = __builtin_amdgcn_mfma_f32_16x16x32_f16(af_, bf_, acc_, 0, 0, 0); \
        }                                                                     \
        int col_ = mrow;                                                      \
        _Pragma("unroll")                                                     \
        for (int rr = 0; rr < 4; ++rr) {                                      \
            int orow_ = tile_ + quad * 4 + rr;                                \
            if (orow_ < M) {                                                  \
                float v_ = acc_[rr];                                          \
                if (col_ < 6) {                                               \
                    zg[(size_t)orow_ * 8 + col_] = f2h(v_);                   \
                } else if (col_ < 12) {                                       \
                    zs[(size_t)orow_ * 6 + (col_ - 6)] = v_ + b3[col_ - 6];   \
                }                                                             \
            }                                                                 \
        }                                                                     \
    }                                                                         \
    __syncthreads();                                                          \
} while (0)

__global__ __launch_bounds__(256, 6) void agg_gemm(
    const __half2* __restrict__ featb,        // [N][64] f16x2 gather table
    const _Float16* __restrict__ Aself,       // [M][128] f16 self rows
    const int* __restrict__ boff,             // [NR*N+1] range-major offsets
    const int* __restrict__ csr,
    const int* __restrict__ deg,              // [N]
    const _Float16* __restrict__ Wc,          // [128][256] f16
    const float* __restrict__ bias,           // [128]
    unsigned short* __restrict__ outb,        // [M][128] f16 (nullable)
    int do_lin3,
    const _Float16* __restrict__ W3c,         // [16][128] f16
    const float* __restrict__ b3,             // [6]
    unsigned short* __restrict__ zg,          // [M][8] f16
    float* __restrict__ zs,                   // [M][6] fp32
    int M, int relu) {
    __shared__ __half2 aggT[16][68];          // 64 + 4 pad (2-way banks = free)
    __shared__ unsigned short h2T[16][136];
    int tid = threadIdx.x;
    int wave = tid >> 6;
    int lane = tid & 63;
    int mrow = lane & 15;
    int quad = lane >> 4;
    int base = blockIdx.x * NPB;
    int w4 = wave * 4;

    // 16 named accumulators: one VGPR each, cannot spill as an array
    __half2 z = __floats2half2_rn(0.f, 0.f);
    __half2 a0 = z, a1 = z, a2 = z, a3 = z, a4 = z, a5 = z, a6 = z, a7 = z;
    __half2 a8 = z, a9 = z, a10 = z, a11 = z, a12 = z, a13 = z, a14 = z, a15 = z;

    // ---- phase 1: src-range-phased gather (all ~1536 blocks resident sweep
    // ranges in the same order; per-XCD L2 holds one 3.2MB slab at a time)
#pragma unroll 1
    for (int r = 0; r < NR; ++r) {
        const int* bo = boff + (size_t)r * N_NODES;
        GATH(a0, 0, 0);  GATH(a1, 0, 1);  GATH(a2, 0, 2);  GATH(a3, 0, 3);
        GATH(a4, 1, 0);  GATH(a5, 1, 1);  GATH(a6, 1, 2);  GATH(a7, 1, 3);
        GATH(a8, 2, 0);  GATH(a9, 2, 1);  GATH(a10, 2, 2); GATH(a11, 2, 3);
        GATH(a12, 3, 0); GATH(a13, 3, 1); GATH(a14, 3, 2); GATH(a15, 3, 3);
    }

    int t0 = wave * 2, t1 = wave * 2 + 1;
    float bc0 = bias[t0 * 16 + mrow];
    float bc1 = bias[t1 * 16 + mrow];

    // ---- phase 2: 4 MFMA tiles of 16 nodes
    TILE_BODY(0, a0, a1, a2, a3);
    TILE_BODY(1, a4, a5, a6, a7);
    TILE_BODY(2, a8, a9, a10, a11);
    TILE_BODY(3, a12, a13, a14, a15);
}

// ------------------------------------------- final: out[n][j] = mean_s zg[s][j] + zs[n][j]
__global__ void out_kernel(const unsigned short* __restrict__ zg,
                           const float* __restrict__ zs,
                           const int* __restrict__ boff,
                           const int* __restrict__ csr,
                           const int* __restrict__ deg,
                           float* __restrict__ out, int M) {
    int idx = blockIdx.x * blockDim.x + threadIdx.x;
    int node = idx >> 3;
    int j = idx & 7;
    if (node >= M || j >= 6) return;
    float acc = 0.f;
#pragma unroll 1
    for (int r = 0; r < NR; ++r) {
        int beg = boff[(size_t)r * N_NODES + node];
        int end = boff[(size_t)r * N_NODES + node + 1];
        for (int i = beg; i < end; ++i) {
            unsigned short u = zg[(size_t)csr[i] * 8 + j];
            acc += __half2float(*(const __half*)&u);
        }
    }
    int dg = deg[node];
    float inv = (dg > 0) ? 1.0f / (float)dg : 0.f;
    out[(size_t)node * 6 + j] = acc * inv + zs[(size_t)node * 6 + j];
}

// ---------------------------------------------------------------- launch
static inline size_t align_up(size_t x, size_t a) { return (x + a - 1) & ~(a - 1); }

extern "C" void kernel_launch(void* const* d_in, const int* in_sizes, int n_in,
                              void* d_out, int out_size, void* d_ws, size_t ws_size,
                              hipStream_t stream) {
    const float* x = (const float*)d_in[0];
    const int* ei = (const int*)d_in[1];
    const float* Wl1 = (const float*)d_in[2];
    const float* Wr1 = (const float*)d_in[3];
    const float* b1 = (const float*)d_in[4];
    const float* Wl2 = (const float*)d_in[5];
    const float* Wr2 = (const float*)d_in[6];
    const float* b2 = (const float*)d_in[7];
    const float* Wl3 = (const float*)d_in[8];
    const float* Wr3 = (const float*)d_in[9];
    const float* b3 = (const float*)d_in[10];

    const int N = in_sizes[0] / 128;   // 100000
    const int E = in_sizes[1] / 2;     // 3200000
    const int* src = ei;
    const int* dst = ei + E;

    // workspace layout
    char* ws = (char*)d_ws;
    size_t off = 0;
    int* cnt = (int*)(ws + off);        off = align_up(off + (size_t)NBINS * 4, 512);
    int* boff = (int*)(ws + off);       off = align_up(off + (size_t)(NBINS + 1) * 4, 512);
    int* block_sums = (int*)(ws + off); off = align_up(off + 512 * 4, 512);
    unsigned int* gcur = (unsigned int*)(ws + off); off = align_up(off + G_PART * 4, 512);
    int* deg = (int*)(ws + off);        off = align_up(off + (size_t)N * 4, 512);
    unsigned short* Wc1 = (unsigned short*)(ws + off); off = align_up(off + 128 * 256 * 2, 512);
    unsigned short* Wc2 = (unsigned short*)(ws + off); off = align_up(off + 128 * 256 * 2, 512);
    unsigned short* W3c = (unsigned short*)(ws + off); off = align_up(off + 16 * 128 * 2, 512);
    int* csr_src = (int*)(ws + off);    off = align_up(off + (size_t)E * 4, 512);
    float* slotA = (float*)(ws + off);  off = align_up(off + (size_t)N * 128 * 4, 512);
    float* slotB = (float*)(ws + off);  off = align_up(off + (size_t)N * 128 * 4, 512);
    uint2* h1b = (uint2*)(ws + off);    off = align_up(off + (size_t)N * 128 * 2, 512);
    // aliases (lifetimes disjoint):
    //  slotA: partial ushort [count..fill] (19.2MB); xb [pack..agg_gemm1] (25.6MB)
    //  slotB: bkt [partition..fill] (14.3MB); zg+zs [agg_gemm2..out] (4MB)
    unsigned short* partial = (unsigned short*)slotA;
    const int cap = 28000;  // per-group mean 25000, +19 sigma
    int* bkt = (int*)slotB;
    uint2* xb = (uint2*)slotA;          // written after fill (partial dead)
    unsigned short* zg = (unsigned short*)slotB;
    float* zs = (float*)((char*)slotB + align_up((size_t)N * 8 * 2, 512));
    (void)ws_size;

    // --- CSR build: radix partition + LDS histogram, (src_range, dst) key
    const int build_grid = G_PART * B_PART;          // 1536 = 6 blocks/CU

    hipMemsetAsync(gcur, 0, G_PART * 4, stream);
    partition_edges<<<A_BLOCKS, 256, 0, stream>>>(src, dst, E, bkt, gcur, cap);
    count_hist<<<build_grid, 256, 0, stream>>>(bkt, gcur, cap, partial);
    scan_partials<<<(NBINS + 255) / 256, 256, 0, stream>>>(partial, cnt);
    deg_kernel<<<(N + 255) / 256, 256, 0, stream>>>(cnt, deg);

    const int nscan = (NBINS + SCHUNK - 1) / SCHUNK;  // 196 <= 256
    scan_blocks<<<nscan, 256, 0, stream>>>(cnt, boff, block_sums, NBINS);
    scan_sums<<<1, 256, 0, stream>>>(block_sums, nscan, boff, NBINS);
    scan_add<<<nscan, 256, 0, stream>>>(boff, block_sums, NBINS);

    fill_hist<<<build_grid, 256, 0, stream>>>(bkt, gcur, cap, partial, boff, csr_src);

    // packs (xb after fill: partial slot is free)
    const int n4 = N * 32;
    pack_f16<<<(n4 + 255) / 256, 256, 0, stream>>>(x, xb, n4);
    pack_weights<<<(65536 + 2048 + 255) / 256, 256, 0, stream>>>(
        Wl1, Wr1, Wl2, Wr2, Wl3, Wr3, Wc1, Wc2, W3c);

    const int aggGrid = (N + NPB - 1) / NPB;   // 1563

    // layer 1: fused gather+GEMM -> h1b (f16)
    agg_gemm<<<aggGrid, 256, 0, stream>>>(
        (const __half2*)xb, (const _Float16*)xb, boff, csr_src, deg,
        (const _Float16*)Wc1, b1, (unsigned short*)h1b,
        0, nullptr, nullptr, nullptr, nullptr, N, 1);
    // layer 2: fused gather+GEMM+lin3 -> zg (f16) + zs (fp32)
    agg_gemm<<<aggGrid, 256, 0, stream>>>(
        (const __half2*)h1b, (const _Float16*)h1b, boff, csr_src, deg,
        (const _Float16*)Wc2, b2, nullptr,
        1, (const _Float16*)W3c, b3, zg, zs, N, 1);
    // final
    out_kernel<<<(N * 8 + 255) / 256, 256, 0, stream>>>(zg, zs, boff, csr_src, deg,
                                                        (float*)d_out, N);
}

// Round 4
// 1035.217 us; speedup vs baseline: 1.5146x; 1.0849x over previous
//
#include <hip/hip_runtime.h>
#include <hip/hip_fp16.h>

#define N_NODES 100000
// R19 = R17 (known-passing) + ONE change: per-range wave-coalesced bound load
// + __shfl broadcast (prefetched one range ahead) replaces the per-segment
// serial global bound loads. R18 changed 4 things at once and failed
// unattributably; this round isolates the bounds-latency variable.
#define G_PART 128
#define NPG 782            // ceil(N/G_PART)
#define NR 8               // src ranges
#define RNG 12500          // nodes per src range (3.2MB f16 slab < 4MB XCD L2)
#define BINS (NPG * NR)    // 6256 bins per dst group
#define BINS_PAD 6272
#define B_PART 12          // blocks per group; grid 1536 = 6 blocks/CU
#define A_BLOCKS 1024
#define NBINS (N_NODES * NR)
#define NPB 64             // nodes per agg_gemm block; grid 1563

// ---------------------------------------------------------------- CSR build
__global__ __launch_bounds__(256) void partition_edges(
    const int* __restrict__ src, const int* __restrict__ dst, int E,
    int* __restrict__ bkt, unsigned int* __restrict__ gcur, int cap) {
    __shared__ int cnt[G_PART];
    __shared__ unsigned int base[G_PART];
    __shared__ unsigned int cur[G_PART];
    int tid = threadIdx.x;
    if (tid < G_PART) cnt[tid] = 0;
    __syncthreads();
    int per = (E + A_BLOCKS - 1) / A_BLOCKS;
    int beg = blockIdx.x * per;
    int end = min(beg + per, E);
    for (int i = beg + tid; i < end; i += 256) {
        int d = dst[i];
        atomicAdd(&cnt[d / NPG], 1);
    }
    __syncthreads();
    if (tid < G_PART) {
        base[tid] = atomicAdd(&gcur[tid], (unsigned int)cnt[tid]);
        cur[tid] = 0;
    }
    __syncthreads();
    for (int i = beg + tid; i < end; i += 256) {
        int d = dst[i];
        int s = src[i];
        int g = d / NPG;
        unsigned int p = base[g] + atomicAdd(&cur[g], 1u);
        bkt[(size_t)g * cap + p] = ((d - g * NPG) << 17) | s;
    }
}

__global__ __launch_bounds__(256) void count_hist(const int* __restrict__ bkt,
                                                  const unsigned int* __restrict__ gcur,
                                                  int cap,
                                                  unsigned short* __restrict__ partial) {
    __shared__ int hist[BINS_PAD];
    int g = blockIdx.x & (G_PART - 1);
    int b = blockIdx.x / G_PART;
    int tid = threadIdx.x;
    for (int i = tid; i < BINS; i += 256) hist[i] = 0;
    __syncthreads();
    int len = (int)gcur[g];
    int per = (len + B_PART - 1) / B_PART;
    int ibeg = b * per;
    int iend = min(ibeg + per, len);
    const int* bp = bkt + (size_t)g * cap;
    for (int i = ibeg + tid; i < iend; i += 256) {
        int v = __builtin_nontemporal_load(bp + i);
        int bin = ((v & 0x1FFFF) / RNG) * NPG + (v >> 17);  // (src_range, local_dst)
        atomicAdd(&hist[bin], 1);
    }
    __syncthreads();
    size_t basep = (size_t)(g * B_PART + b) * BINS;
    for (int j = tid; j < BINS; j += 256) partial[basep + j] = (unsigned short)hist[j];
}

// global bin order is RANGE-MAJOR: B = r*N + dst  (csr is range-major)
__global__ __launch_bounds__(256) void scan_partials(unsigned short* __restrict__ partial,
                                                     int* __restrict__ cnt) {
    int B = blockIdx.x * 256 + threadIdx.x;
    if (B >= NBINS) return;
    int r = B / N_NODES;
    int dstn = B - r * N_NODES;
    int g = dstn / NPG;
    int i = r * NPG + (dstn - g * NPG);
    size_t basep = (size_t)g * B_PART * BINS + i;
    int run = 0;
#pragma unroll 4
    for (int b = 0; b < B_PART; ++b) {
        size_t idx = basep + (size_t)b * BINS;
        int t = partial[idx];
        partial[idx] = (unsigned short)run;
        run += t;
    }
    cnt[B] = run;
}

__global__ __launch_bounds__(256) void deg_kernel(const int* __restrict__ cnt,
                                                  int* __restrict__ deg) {
    int n = blockIdx.x * 256 + threadIdx.x;
    if (n >= N_NODES) return;
    int s = 0;
#pragma unroll
    for (int r = 0; r < NR; ++r) s += cnt[(size_t)r * N_NODES + n];
    deg[n] = s;
}

// ---------------- grid-parallel exclusive scan over NBINS
#define SCHUNK 4096

__global__ __launch_bounds__(256) void scan_blocks(const int* __restrict__ cnt,
                                                   int* __restrict__ boff,
                                                   int* __restrict__ block_sums, int n) {
    __shared__ int ts[256];
    int tid = threadIdx.x;
    int base = blockIdx.x * SCHUNK + tid * 16;
    int v[16];
    int s = 0;
#pragma unroll
    for (int j = 0; j < 16; ++j) {
        int i = base + j;
        v[j] = (i < n) ? cnt[i] : 0;
        s += v[j];
    }
    ts[tid] = s;
    __syncthreads();
    for (int off = 1; off < 256; off <<= 1) {
        int t = 0;
        if (tid >= off) t = ts[tid - off];
        __syncthreads();
        if (tid >= off) ts[tid] += t;
        __syncthreads();
    }
    int run = (tid > 0) ? ts[tid - 1] : 0;
    if (tid == 255) block_sums[blockIdx.x] = ts[255];
#pragma unroll
    for (int j = 0; j < 16; ++j) {
        int i = base + j;
        if (i < n) boff[i] = run;
        run += v[j];
    }
}

__global__ __launch_bounds__(256) void scan_sums(int* __restrict__ block_sums, int nb,
                                                 int* __restrict__ boff, int n) {
    __shared__ int ts[256];
    int tid = threadIdx.x;
    int v = (tid < nb) ? block_sums[tid] : 0;
    ts[tid] = v;
    __syncthreads();
    for (int off = 1; off < 256; off <<= 1) {
        int t = 0;
        if (tid >= off) t = ts[tid - off];
        __syncthreads();
        if (tid >= off) ts[tid] += t;
        __syncthreads();
    }
    if (tid < nb) block_sums[tid] = (tid > 0) ? ts[tid - 1] : 0;
    if (tid == 255) boff[n] = ts[255];
}

__global__ __launch_bounds__(256) void scan_add(int* __restrict__ boff,
                                                const int* __restrict__ block_sums, int n) {
    int tid = threadIdx.x;
    int off = block_sums[blockIdx.x];
    int base = blockIdx.x * SCHUNK + tid * 16;
#pragma unroll
    for (int j = 0; j < 16; ++j) {
        int i = base + j;
        if (i < n) boff[i] += off;
    }
}

__global__ __launch_bounds__(256) void fill_hist(const int* __restrict__ bkt,
                                                 const unsigned int* __restrict__ gcur,
                                                 int cap,
                                                 const unsigned short* __restrict__ partial,
                                                 const int* __restrict__ boff,
                                                 int* __restrict__ csr_src) {
    __shared__ int cur[BINS_PAD];
    int g = blockIdx.x & (G_PART - 1);
    int b = blockIdx.x / G_PART;
    int tid = threadIdx.x;
    size_t pbase = (size_t)(g * B_PART + b) * BINS;
    for (int i = tid; i < BINS; i += 256) {
        int r = i / NPG;
        int dstn = g * NPG + (i - r * NPG);
        if (dstn < N_NODES)
            cur[i] = boff[(size_t)r * N_NODES + dstn] + (int)partial[pbase + i];
    }
    __syncthreads();
    int len = (int)gcur[g];
    int per = (len + B_PART - 1) / B_PART;
    int ibeg = b * per;
    int iend = min(ibeg + per, len);
    const int* bp = bkt + (size_t)g * cap;
    for (int i = ibeg + tid; i < iend; i += 256) {
        int v = __builtin_nontemporal_load(bp + i);
        int bin = ((v & 0x1FFFF) / RNG) * NPG + (v >> 17);
        int p = atomicAdd(&cur[bin], 1);
        csr_src[p] = v & 0x1FFFF;
    }
}

// ---------------------------------------------------------------- f16 packs
__global__ __launch_bounds__(256) void pack_f16(const float* __restrict__ in,
                                                uint2* __restrict__ out, int n4) {
    int i = blockIdx.x * 256 + threadIdx.x;
    if (i >= n4) return;
    float4 v = *(const float4*)&in[(size_t)i * 4];
    __half2 p0 = __floats2half2_rn(v.x, v.y);
    __half2 p1 = __floats2half2_rn(v.z, v.w);
    uint2 o;
    o.x = *(const uint*)&p0;
    o.y = *(const uint*)&p1;
    out[i] = o;
}

static __device__ inline unsigned short f2h(float v) {
    __half h = __float2half(v);
    return *(const unsigned short*)&h;
}

__global__ __launch_bounds__(256) void pack_weights(
    const float* __restrict__ Wl1, const float* __restrict__ Wr1,
    const float* __restrict__ Wl2, const float* __restrict__ Wr2,
    const float* __restrict__ Wl3, const float* __restrict__ Wr3,
    unsigned short* __restrict__ Wc1, unsigned short* __restrict__ Wc2,
    unsigned short* __restrict__ W3c) {
    int idx = blockIdx.x * 256 + threadIdx.x;
    if (idx < 32768) {
        int n = idx >> 8, k = idx & 255;
        Wc1[idx] = f2h((k < 128) ? Wl1[n * 128 + k] : Wr1[n * 128 + (k - 128)]);
    } else if (idx < 65536) {
        int t = idx - 32768;
        int n = t >> 8, k = t & 255;
        Wc2[t] = f2h((k < 128) ? Wl2[n * 128 + k] : Wr2[n * 128 + (k - 128)]);
    } else if (idx < 65536 + 2048) {
        int t = idx - 65536;
        int n = t >> 7, k = t & 127;
        float v = (n < 6) ? Wl3[n * 128 + k] : ((n < 12) ? Wr3[(n - 6) * 128 + k] : 0.f);
        W3c[t] = f2h(v);
    }
}

// --------------------------------------------- fused agg + MFMA GEMM (+lin3)
typedef __attribute__((ext_vector_type(8))) _Float16 hfrag8;
typedef __attribute__((ext_vector_type(4))) float f32x4;

// per-range bound fetch: lane 2k -> begin of wave-node k, lane 2k+1 -> end
// (= begin of node k+1; boff is contiguous over nodes within a range)
static __device__ inline int load_bounds(const int* __restrict__ boff_r,
                                         int base, int w4, int lane, int M) {
    int bb = 0;
    if (lane < 32) {
        int k = lane >> 1;
        int node = base + (k >> 2) * 16 + w4 + (k & 3) + (lane & 1);
        if (node > M) node = M;
        bb = boff_r[node];
    }
    return bb;
}

// gather one (node, range) segment into a NAMED __half2 accumulator;
// bounds come from the wave-broadcast bb_cur (no dependent global loads)
#define GATH(ACC, T, S) do {                                                  \
    int node_ = base + (T)*16 + w4 + (S);                                     \
    if (node_ < M) {                                                          \
        int k2_ = ((T)*4 + (S)) * 2;                                          \
        int beg_ = __shfl(bb_cur, k2_);                                       \
        int end_ = __shfl(bb_cur, k2_ + 1);                                   \
        int i_ = beg_;                                                        \
        for (; i_ + 4 <= end_; i_ += 4) {                                     \
            int s0_ = csr[i_], s1_ = csr[i_ + 1];                             \
            int s2_ = csr[i_ + 2], s3_ = csr[i_ + 3];                         \
            __half2 v0_ = featb[(uint)s0_ * 64u + lane];                      \
            __half2 v1_ = featb[(uint)s1_ * 64u + lane];                      \
            __half2 v2_ = featb[(uint)s2_ * 64u + lane];                      \
            __half2 v3_ = featb[(uint)s3_ * 64u + lane];                      \
            ACC = __hadd2(ACC, __hadd2(__hadd2(v0_, v1_), __hadd2(v2_, v3_)));\
        }                                                                     \
        for (; i_ < end_; ++i_)                                               \
            ACC = __hadd2(ACC, featb[(uint)csr[i_] * 64u + lane]);            \
    }                                                                         \
} while (0)

#define STAGE1(ACC, T, S) do {                                                \
    int node_ = base + (T)*16 + w4 + (S);                                     \
    float iv_ = 0.f;                                                          \
    if (node_ < M) {                                                          \
        int dg_ = deg[node_];                                                 \
        iv_ = (dg_ > 0) ? 1.0f / (float)dg_ : 0.f;                            \
    }                                                                         \
    float2 f_ = __half22float2(ACC);                                          \
    aggT[w4 + (S)][lane] = __floats2half2_rn(f_.x * iv_, f_.y * iv_);         \
} while (0)

#define TILE_BODY(T, A0, A1, A2, A3) do {                                     \
    int tile_ = base + (T)*16;                                                \
    STAGE1(A0, T, 0); STAGE1(A1, T, 1); STAGE1(A2, T, 2); STAGE1(A3, T, 3);   \
    int row_ = tile_ + mrow;                                                  \
    int rc_ = (row_ < M) ? row_ : 0;                                          \
    const _Float16* arow_ = Aself + (size_t)rc_ * 128;                        \
    hfrag8 as0_ = *(const hfrag8*)(arow_ + 0 * 32 + quad * 8);                \
    hfrag8 as1_ = *(const hfrag8*)(arow_ + 1 * 32 + quad * 8);                \
    hfrag8 as2_ = *(const hfrag8*)(arow_ + 2 * 32 + quad * 8);                \
    hfrag8 as3_ = *(const hfrag8*)(arow_ + 3 * 32 + quad * 8);                \
    __syncthreads();                                                          \
    f32x4 acc0_ = (f32x4){0.f, 0.f, 0.f, 0.f};                                \
    f32x4 acc1_ = (f32x4){0.f, 0.f, 0.f, 0.f};                                \
    _Pragma("unroll")                                                         \
    for (int ks = 0; ks < 8; ++ks) {                                          \
        hfrag8 af_;                                                           \
        if (ks < 4) af_ = *(const hfrag8*)&aggT[mrow][ks * 16 + quad * 4];    \
        else af_ = (ks == 4) ? as0_ : ((ks == 5) ? as1_ : ((ks == 6) ? as2_ : as3_)); \
        hfrag8 bf0_ = *(const hfrag8*)(Wc + (size_t)(t0 * 16 + mrow) * 256 + ks * 32 + quad * 8); \
        hfrag8 bf1_ = *(const hfrag8*)(Wc + (size_t)(t1 * 16 + mrow) * 256 + ks * 32 + quad * 8); \
        acc0_ = __builtin_amdgcn_mfma_f32_16x16x32_f16(af_, bf0_, acc0_, 0, 0, 0); \
        acc1_ = __builtin_amdgcn_mfma_f32_16x16x32_f16(af_, bf1_, acc1_, 0, 0, 0); \
    }                                                                         \
    _Pragma("unroll")                                                         \
    for (int tt = 0; tt < 2; ++tt) {                                          \
        f32x4 a_ = tt ? acc1_ : acc0_;                                        \
        int col_ = (wave * 2 + tt) * 16 + mrow;                               \
        float bc_ = tt ? bc1 : bc0;                                           \
        _Pragma("unroll")                                                     \
        for (int rr = 0; rr < 4; ++rr) {                                      \
            float v_ = a_[rr] + bc_;                                          \
            if (relu) v_ = fmaxf(v_, 0.f);                                    \
            h2T[quad * 4 + rr][col_] = f2h(v_);                               \
        }                                                                     \
    }                                                                         \
    __syncthreads();                                                          \
    if (outb) {                                                               \
        int rr_ = tid >> 4;                                                   \
        int c8_ = (tid & 15) * 8;                                             \
        int orow_ = tile_ + rr_;                                              \
        if (orow_ < M)                                                        \
            *(uint4*)&outb[(size_t)orow_ * 128 + c8_] = *(const uint4*)&h2T[rr_][c8_]; \
    }                                                                         \
    if (do_lin3 && wave == 0) {                                               \
        f32x4 acc_ = (f32x4){0.f, 0.f, 0.f, 0.f};                             \
        _Pragma("unroll")                                                     \
        for (int ks = 0; ks < 4; ++ks) {                                      \
            hfrag8 af_ = *(const hfrag8*)&h2T[mrow][ks * 32 + quad * 8];      \
            hfrag8 bf_ = *(const hfrag8*)(W3c + (size_t)mrow * 128 + ks * 32 + quad * 8); \
            acc_ = __builtin_amdgcn_mfma_f32_16x16x32_f16(af_, bf_, acc_, 0, 0, 0); \
        }                                                                     \
        int col_ = mrow;                                                      \
        _Pragma("unroll")                                                     \
        for (int rr = 0; rr < 4; ++rr) {                                      \
            int orow_ = tile_ + quad * 4 + rr;                                \
            if (orow_ < M) {                                                  \
                float v_ = acc_[rr];                                          \
                if (col_ < 6) {                                               \
                    zg[(size_t)orow_ * 8 + col_] = f2h(v_);                   \
                } else if (col_ < 12) {                                       \
                    zs[(size_t)orow_ * 6 + (col_ - 6)] = v_ + b3[col_ - 6];   \
                }                                                             \
            }                                                                 \
        }                                                                     \
    }                                                                         \
    __syncthreads();                                                          \
} while (0)

__global__ __launch_bounds__(256, 6) void agg_gemm(
    const __half2* __restrict__ featb,        // [N][64] f16x2 gather table
    const _Float16* __restrict__ Aself,       // [M][128] f16 self rows
    const int* __restrict__ boff,             // [NR*N+1] range-major offsets
    const int* __restrict__ csr,
    const int* __restrict__ deg,              // [N]
    const _Float16* __restrict__ Wc,          // [128][256] f16
    const float* __restrict__ bias,           // [128]
    unsigned short* __restrict__ outb,        // [M][128] f16 (nullable)
    int do_lin3,
    const _Float16* __restrict__ W3c,         // [16][128] f16
    const float* __restrict__ b3,             // [6]
    unsigned short* __restrict__ zg,          // [M][8] f16
    float* __restrict__ zs,                   // [M][6] fp32
    int M, int relu) {
    __shared__ __half2 aggT[16][68];          // 64 + 4 pad (2-way banks = free)
    __shared__ unsigned short h2T[16][136];
    int tid = threadIdx.x;
    int wave = tid >> 6;
    int lane = tid & 63;
    int mrow = lane & 15;
    int quad = lane >> 4;
    int base = blockIdx.x * NPB;
    int w4 = wave * 4;

    // 16 named accumulators: one VGPR each, cannot spill as an array
    __half2 z = __floats2half2_rn(0.f, 0.f);
    __half2 a0 = z, a1 = z, a2 = z, a3 = z, a4 = z, a5 = z, a6 = z, a7 = z;
    __half2 a8 = z, a9 = z, a10 = z, a11 = z, a12 = z, a13 = z, a14 = z, a15 = z;

    // ---- phase 1: src-range-phased gather. Bounds for all 16 wave-nodes of
    // range r arrive via ONE coalesced 32-lane load + shfl broadcast, and the
    // next range's bounds prefetch under the current range's gather.
    int bb_cur = load_bounds(boff, base, w4, lane, M);
#pragma unroll 1
    for (int r = 0; r < NR; ++r) {
        int bb_nxt = (r + 1 < NR)
            ? load_bounds(boff + (size_t)(r + 1) * N_NODES, base, w4, lane, M) : 0;
        GATH(a0, 0, 0);  GATH(a1, 0, 1);  GATH(a2, 0, 2);  GATH(a3, 0, 3);
        GATH(a4, 1, 0);  GATH(a5, 1, 1);  GATH(a6, 1, 2);  GATH(a7, 1, 3);
        GATH(a8, 2, 0);  GATH(a9, 2, 1);  GATH(a10, 2, 2); GATH(a11, 2, 3);
        GATH(a12, 3, 0); GATH(a13, 3, 1); GATH(a14, 3, 2); GATH(a15, 3, 3);
        bb_cur = bb_nxt;
    }

    int t0 = wave * 2, t1 = wave * 2 + 1;
    float bc0 = bias[t0 * 16 + mrow];
    float bc1 = bias[t1 * 16 + mrow];

    // ---- phase 2: 4 MFMA tiles of 16 nodes (R17 verbatim)
    TILE_BODY(0, a0, a1, a2, a3);
    TILE_BODY(1, a4, a5, a6, a7);
    TILE_BODY(2, a8, a9, a10, a11);
    TILE_BODY(3, a12, a13, a14, a15);
}

// ------------------------------------------- final: out[n][j] = mean_s zg[s][j] + zs[n][j]
__global__ void out_kernel(const unsigned short* __restrict__ zg,
                           const float* __restrict__ zs,
                           const int* __restrict__ boff,
                           const int* __restrict__ csr,
                           const int* __restrict__ deg,
                           float* __restrict__ out, int M) {
    int idx = blockIdx.x * blockDim.x + threadIdx.x;
    int node = idx >> 3;
    int j = idx & 7;
    if (node >= M || j >= 6) return;
    float acc = 0.f;
#pragma unroll 1
    for (int r = 0; r < NR; ++r) {
        int beg = boff[(size_t)r * N_NODES + node];
        int end = boff[(size_t)r * N_NODES + node + 1];
        for (int i = beg; i < end; ++i) {
            unsigned short u = zg[(size_t)csr[i] * 8 + j];
            acc += __half2float(*(const __half*)&u);
        }
    }
    int dg = deg[node];
    float inv = (dg > 0) ? 1.0f / (float)dg : 0.f;
    out[(size_t)node * 6 + j] = acc * inv + zs[(size_t)node * 6 + j];
}

// ---------------------------------------------------------------- launch
static inline size_t align_up(size_t x, size_t a) { return (x + a - 1) & ~(a - 1); }

extern "C" void kernel_launch(void* const* d_in, const int* in_sizes, int n_in,
                              void* d_out, int out_size, void* d_ws, size_t ws_size,
                              hipStream_t stream) {
    const float* x = (const float*)d_in[0];
    const int* ei = (const int*)d_in[1];
    const float* Wl1 = (const float*)d_in[2];
    const float* Wr1 = (const float*)d_in[3];
    const float* b1 = (const float*)d_in[4];
    const float* Wl2 = (const float*)d_in[5];
    const float* Wr2 = (const float*)d_in[6];
    const float* b2 = (const float*)d_in[7];
    const float* Wl3 = (const float*)d_in[8];
    const float* Wr3 = (const float*)d_in[9];
    const float* b3 = (const float*)d_in[10];

    const int N = in_sizes[0] / 128;   // 100000
    const int E = in_sizes[1] / 2;     // 3200000
    const int* src = ei;
    const int* dst = ei + E;

    // workspace layout
    char* ws = (char*)d_ws;
    size_t off = 0;
    int* cnt = (int*)(ws + off);        off = align_up(off + (size_t)NBINS * 4, 512);
    int* boff = (int*)(ws + off);       off = align_up(off + (size_t)(NBINS + 1) * 4, 512);
    int* block_sums = (int*)(ws + off); off = align_up(off + 512 * 4, 512);
    unsigned int* gcur = (unsigned int*)(ws + off); off = align_up(off + G_PART * 4, 512);
    int* deg = (int*)(ws + off);        off = align_up(off + (size_t)N * 4, 512);
    unsigned short* Wc1 = (unsigned short*)(ws + off); off = align_up(off + 128 * 256 * 2, 512);
    unsigned short* Wc2 = (unsigned short*)(ws + off); off = align_up(off + 128 * 256 * 2, 512);
    unsigned short* W3c = (unsigned short*)(ws + off); off = align_up(off + 16 * 128 * 2, 512);
    int* csr_src = (int*)(ws + off);    off = align_up(off + (size_t)E * 4, 512);
    float* slotA = (float*)(ws + off);  off = align_up(off + (size_t)N * 128 * 4, 512);
    float* slotB = (float*)(ws + off);  off = align_up(off + (size_t)N * 128 * 4, 512);
    uint2* h1b = (uint2*)(ws + off);    off = align_up(off + (size_t)N * 128 * 2, 512);
    // aliases (lifetimes disjoint):
    //  slotA: partial ushort [count..fill] (19.2MB); xb [pack..agg_gemm1] (25.6MB)
    //  slotB: bkt [partition..fill] (14.3MB); zg+zs [agg_gemm2..out] (4MB)
    unsigned short* partial = (unsigned short*)slotA;
    const int cap = 28000;  // per-group mean 25000, +19 sigma
    int* bkt = (int*)slotB;
    uint2* xb = (uint2*)slotA;          // written after fill (partial dead)
    unsigned short* zg = (unsigned short*)slotB;
    float* zs = (float*)((char*)slotB + align_up((size_t)N * 8 * 2, 512));
    (void)ws_size;

    // --- CSR build: radix partition + LDS histogram, (src_range, dst) key
    const int build_grid = G_PART * B_PART;          // 1536 = 6 blocks/CU

    hipMemsetAsync(gcur, 0, G_PART * 4, stream);
    partition_edges<<<A_BLOCKS, 256, 0, stream>>>(src, dst, E, bkt, gcur, cap);
    count_hist<<<build_grid, 256, 0, stream>>>(bkt, gcur, cap, partial);
    scan_partials<<<(NBINS + 255) / 256, 256, 0, stream>>>(partial, cnt);
    deg_kernel<<<(N + 255) / 256, 256, 0, stream>>>(cnt, deg);

    const int nscan = (NBINS + SCHUNK - 1) / SCHUNK;  // 196 <= 256
    scan_blocks<<<nscan, 256, 0, stream>>>(cnt, boff, block_sums, NBINS);
    scan_sums<<<1, 256, 0, stream>>>(block_sums, nscan, boff, NBINS);
    scan_add<<<nscan, 256, 0, stream>>>(boff, block_sums, NBINS);

    fill_hist<<<build_grid, 256, 0, stream>>>(bkt, gcur, cap, partial, boff, csr_src);

    // packs (xb after fill: partial slot is free)
    const int n4 = N * 32;
    pack_f16<<<(n4 + 255) / 256, 256, 0, stream>>>(x, xb, n4);
    pack_weights<<<(65536 + 2048 + 255) / 256, 256, 0, stream>>>(
        Wl1, Wr1, Wl2, Wr2, Wl3, Wr3, Wc1, Wc2, W3c);

    const int aggGrid = (N + NPB - 1) / NPB;   // 1563

    // layer 1: fused gather+GEMM -> h1b (f16)
    agg_gemm<<<aggGrid, 256, 0, stream>>>(
        (const __half2*)xb, (const _Float16*)xb, boff, csr_src, deg,
        (const _Float16*)Wc1, b1, (unsigned short*)h1b,
        0, nullptr, nullptr, nullptr, nullptr, N, 1);
    // layer 2: fused gather+GEMM+lin3 -> zg (f16) + zs (fp32)
    agg_gemm<<<aggGrid, 256, 0, stream>>>(
        (const __half2*)h1b, (const _Float16*)h1b, boff, csr_src, deg,
        (const _Float16*)Wc2, b2, nullptr,
        1, (const _Float16*)W3c, b3, zg, zs, N, 1);
    // final
    out_kernel<<<(N * 8 + 255) / 256, 256, 0, stream>>>(zg, zs, boff, csr_src, deg,
                                                        (float*)d_out, N);
}

// Round 5
// 835.344 us; speedup vs baseline: 1.8770x; 1.2393x over previous
//
#include <hip/hip_runtime.h>
#include <hip/hip_fp16.h>

#define N_NODES 100000
// R20 = R19 (passing) + ONE change: GATH4 span-fused chunked gather.
// The 4 nodes of each gather group are contiguous, so their csr rows form one
// contiguous span; walk it in 8-edge chunks (8 clamped csr loads -> 1 wait ->
// 8 featb loads -> 1 wait -> uniform-branch accumulator routing). Replaces
// per-segment serial loops (~5 waits/segment incl. scalar remainder) with
// ~2 waits/chunk: ~640 -> ~140 waits per wave. Everything else R19-verbatim.
#define G_PART 128
#define NPG 782            // ceil(N/G_PART)
#define NR 8               // src ranges
#define RNG 12500          // nodes per src range (3.2MB f16 slab < 4MB XCD L2)
#define BINS (NPG * NR)    // 6256 bins per dst group
#define BINS_PAD 6272
#define B_PART 12          // blocks per group; grid 1536 = 6 blocks/CU
#define A_BLOCKS 1024
#define NBINS (N_NODES * NR)
#define NPB 64             // nodes per agg_gemm block; grid 1563

// ---------------------------------------------------------------- CSR build
__global__ __launch_bounds__(256) void partition_edges(
    const int* __restrict__ src, const int* __restrict__ dst, int E,
    int* __restrict__ bkt, unsigned int* __restrict__ gcur, int cap) {
    __shared__ int cnt[G_PART];
    __shared__ unsigned int base[G_PART];
    __shared__ unsigned int cur[G_PART];
    int tid = threadIdx.x;
    if (tid < G_PART) cnt[tid] = 0;
    __syncthreads();
    int per = (E + A_BLOCKS - 1) / A_BLOCKS;
    int beg = blockIdx.x * per;
    int end = min(beg + per, E);
    for (int i = beg + tid; i < end; i += 256) {
        int d = dst[i];
        atomicAdd(&cnt[d / NPG], 1);
    }
    __syncthreads();
    if (tid < G_PART) {
        base[tid] = atomicAdd(&gcur[tid], (unsigned int)cnt[tid]);
        cur[tid] = 0;
    }
    __syncthreads();
    for (int i = beg + tid; i < end; i += 256) {
        int d = dst[i];
        int s = src[i];
        int g = d / NPG;
        unsigned int p = base[g] + atomicAdd(&cur[g], 1u);
        bkt[(size_t)g * cap + p] = ((d - g * NPG) << 17) | s;
    }
}

__global__ __launch_bounds__(256) void count_hist(const int* __restrict__ bkt,
                                                  const unsigned int* __restrict__ gcur,
                                                  int cap,
                                                  unsigned short* __restrict__ partial) {
    __shared__ int hist[BINS_PAD];
    int g = blockIdx.x & (G_PART - 1);
    int b = blockIdx.x / G_PART;
    int tid = threadIdx.x;
    for (int i = tid; i < BINS; i += 256) hist[i] = 0;
    __syncthreads();
    int len = (int)gcur[g];
    int per = (len + B_PART - 1) / B_PART;
    int ibeg = b * per;
    int iend = min(ibeg + per, len);
    const int* bp = bkt + (size_t)g * cap;
    for (int i = ibeg + tid; i < iend; i += 256) {
        int v = __builtin_nontemporal_load(bp + i);
        int bin = ((v & 0x1FFFF) / RNG) * NPG + (v >> 17);  // (src_range, local_dst)
        atomicAdd(&hist[bin], 1);
    }
    __syncthreads();
    size_t basep = (size_t)(g * B_PART + b) * BINS;
    for (int j = tid; j < BINS; j += 256) partial[basep + j] = (unsigned short)hist[j];
}

// global bin order is RANGE-MAJOR: B = r*N + dst  (csr is range-major)
__global__ __launch_bounds__(256) void scan_partials(unsigned short* __restrict__ partial,
                                                     int* __restrict__ cnt) {
    int B = blockIdx.x * 256 + threadIdx.x;
    if (B >= NBINS) return;
    int r = B / N_NODES;
    int dstn = B - r * N_NODES;
    int g = dstn / NPG;
    int i = r * NPG + (dstn - g * NPG);
    size_t basep = (size_t)g * B_PART * BINS + i;
    int run = 0;
#pragma unroll 4
    for (int b = 0; b < B_PART; ++b) {
        size_t idx = basep + (size_t)b * BINS;
        int t = partial[idx];
        partial[idx] = (unsigned short)run;
        run += t;
    }
    cnt[B] = run;
}

__global__ __launch_bounds__(256) void deg_kernel(const int* __restrict__ cnt,
                                                  int* __restrict__ deg) {
    int n = blockIdx.x * 256 + threadIdx.x;
    if (n >= N_NODES) return;
    int s = 0;
#pragma unroll
    for (int r = 0; r < NR; ++r) s += cnt[(size_t)r * N_NODES + n];
    deg[n] = s;
}

// ---------------- grid-parallel exclusive scan over NBINS
#define SCHUNK 4096

__global__ __launch_bounds__(256) void scan_blocks(const int* __restrict__ cnt,
                                                   int* __restrict__ boff,
                                                   int* __restrict__ block_sums, int n) {
    __shared__ int ts[256];
    int tid = threadIdx.x;
    int base = blockIdx.x * SCHUNK + tid * 16;
    int v[16];
    int s = 0;
#pragma unroll
    for (int j = 0; j < 16; ++j) {
        int i = base + j;
        v[j] = (i < n) ? cnt[i] : 0;
        s += v[j];
    }
    ts[tid] = s;
    __syncthreads();
    for (int off = 1; off < 256; off <<= 1) {
        int t = 0;
        if (tid >= off) t = ts[tid - off];
        __syncthreads();
        if (tid >= off) ts[tid] += t;
        __syncthreads();
    }
    int run = (tid > 0) ? ts[tid - 1] : 0;
    if (tid == 255) block_sums[blockIdx.x] = ts[255];
#pragma unroll
    for (int j = 0; j < 16; ++j) {
        int i = base + j;
        if (i < n) boff[i] = run;
        run += v[j];
    }
}

__global__ __launch_bounds__(256) void scan_sums(int* __restrict__ block_sums, int nb,
                                                 int* __restrict__ boff, int n) {
    __shared__ int ts[256];
    int tid = threadIdx.x;
    int v = (tid < nb) ? block_sums[tid] : 0;
    ts[tid] = v;
    __syncthreads();
    for (int off = 1; off < 256; off <<= 1) {
        int t = 0;
        if (tid >= off) t = ts[tid - off];
        __syncthreads();
        if (tid >= off) ts[tid] += t;
        __syncthreads();
    }
    if (tid < nb) block_sums[tid] = (tid > 0) ? ts[tid - 1] : 0;
    if (tid == 255) boff[n] = ts[255];
}

__global__ __launch_bounds__(256) void scan_add(int* __restrict__ boff,
                                                const int* __restrict__ block_sums, int n) {
    int tid = threadIdx.x;
    int off = block_sums[blockIdx.x];
    int base = blockIdx.x * SCHUNK + tid * 16;
#pragma unroll
    for (int j = 0; j < 16; ++j) {
        int i = base + j;
        if (i < n) boff[i] += off;
    }
}

__global__ __launch_bounds__(256) void fill_hist(const int* __restrict__ bkt,
                                                 const unsigned int* __restrict__ gcur,
                                                 int cap,
                                                 const unsigned short* __restrict__ partial,
                                                 const int* __restrict__ boff,
                                                 int* __restrict__ csr_src) {
    __shared__ int cur[BINS_PAD];
    int g = blockIdx.x & (G_PART - 1);
    int b = blockIdx.x / G_PART;
    int tid = threadIdx.x;
    size_t pbase = (size_t)(g * B_PART + b) * BINS;
    for (int i = tid; i < BINS; i += 256) {
        int r = i / NPG;
        int dstn = g * NPG + (i - r * NPG);
        if (dstn < N_NODES)
            cur[i] = boff[(size_t)r * N_NODES + dstn] + (int)partial[pbase + i];
    }
    __syncthreads();
    int len = (int)gcur[g];
    int per = (len + B_PART - 1) / B_PART;
    int ibeg = b * per;
    int iend = min(ibeg + per, len);
    const int* bp = bkt + (size_t)g * cap;
    for (int i = ibeg + tid; i < iend; i += 256) {
        int v = __builtin_nontemporal_load(bp + i);
        int bin = ((v & 0x1FFFF) / RNG) * NPG + (v >> 17);
        int p = atomicAdd(&cur[bin], 1);
        csr_src[p] = v & 0x1FFFF;
    }
}

// ---------------------------------------------------------------- f16 packs
__global__ __launch_bounds__(256) void pack_f16(const float* __restrict__ in,
                                                uint2* __restrict__ out, int n4) {
    int i = blockIdx.x * 256 + threadIdx.x;
    if (i >= n4) return;
    float4 v = *(const float4*)&in[(size_t)i * 4];
    __half2 p0 = __floats2half2_rn(v.x, v.y);
    __half2 p1 = __floats2half2_rn(v.z, v.w);
    uint2 o;
    o.x = *(const uint*)&p0;
    o.y = *(const uint*)&p1;
    out[i] = o;
}

static __device__ inline unsigned short f2h(float v) {
    __half h = __float2half(v);
    return *(const unsigned short*)&h;
}

__global__ __launch_bounds__(256) void pack_weights(
    const float* __restrict__ Wl1, const float* __restrict__ Wr1,
    const float* __restrict__ Wl2, const float* __restrict__ Wr2,
    const float* __restrict__ Wl3, const float* __restrict__ Wr3,
    unsigned short* __restrict__ Wc1, unsigned short* __restrict__ Wc2,
    unsigned short* __restrict__ W3c) {
    int idx = blockIdx.x * 256 + threadIdx.x;
    if (idx < 32768) {
        int n = idx >> 8, k = idx & 255;
        Wc1[idx] = f2h((k < 128) ? Wl1[n * 128 + k] : Wr1[n * 128 + (k - 128)]);
    } else if (idx < 65536) {
        int t = idx - 32768;
        int n = t >> 8, k = t & 255;
        Wc2[t] = f2h((k < 128) ? Wl2[n * 128 + k] : Wr2[n * 128 + (k - 128)]);
    } else if (idx < 65536 + 2048) {
        int t = idx - 65536;
        int n = t >> 7, k = t & 127;
        float v = (n < 6) ? Wl3[n * 128 + k] : ((n < 12) ? Wr3[(n - 6) * 128 + k] : 0.f);
        W3c[t] = f2h(v);
    }
}

// --------------------------------------------- fused agg + MFMA GEMM (+lin3)
typedef __attribute__((ext_vector_type(8))) _Float16 hfrag8;
typedef __attribute__((ext_vector_type(4))) float f32x4;

// per-range bound fetch: lane 2k -> begin of wave-node k, lane 2k+1 -> end
// (= begin of node k+1; boff is contiguous over nodes within a range)
static __device__ inline int load_bounds(const int* __restrict__ boff_r,
                                         int base, int w4, int lane, int M) {
    int bb = 0;
    if (lane < 32) {
        int k = lane >> 1;
        int node = base + (k >> 2) * 16 + w4 + (k & 3) + (lane & 1);
        if (node > M) node = M;
        bb = boff_r[node];
    }
    return bb;
}

// span-fused gather for group T (4 contiguous nodes): walk [B,E) in 8-edge
// chunks; 2 waits per chunk; route each edge to its accumulator by the
// lane-uniform internal boundaries e0..e2.
#define GATH4(A0, A1, A2, A3, T) do {                                         \
    int k8_ = (T) * 8;                                                        \
    int B_  = __shfl(bb_cur, k8_ + 0);                                        \
    int e0_ = __shfl(bb_cur, k8_ + 1);                                        \
    int e1_ = __shfl(bb_cur, k8_ + 3);                                        \
    int e2_ = __shfl(bb_cur, k8_ + 5);                                        \
    int E_  = __shfl(bb_cur, k8_ + 7);                                        \
    for (int i_ = B_; i_ < E_; i_ += 8) {                                     \
        int c_[8];                                                            \
        _Pragma("unroll")                                                     \
        for (int j = 0; j < 8; ++j) {                                         \
            int idx_ = i_ + j;                                                \
            if (idx_ > E_ - 1) idx_ = E_ - 1;                                 \
            c_[j] = csr[idx_];                                                \
        }                                                                     \
        __half2 f_[8];                                                        \
        _Pragma("unroll")                                                     \
        for (int j = 0; j < 8; ++j)                                           \
            f_[j] = featb[(uint)c_[j] * 64u + lane];                          \
        _Pragma("unroll")                                                     \
        for (int j = 0; j < 8; ++j) {                                         \
            int gi_ = i_ + j;                                                 \
            if (gi_ < E_) {                                                   \
                __half2 v_ = f_[j];                                           \
                if (gi_ < e0_)      A0 = __hadd2(A0, v_);                     \
                else if (gi_ < e1_) A1 = __hadd2(A1, v_);                     \
                else if (gi_ < e2_) A2 = __hadd2(A2, v_);                     \
                else                A3 = __hadd2(A3, v_);                     \
            }                                                                 \
        }                                                                     \
    }                                                                         \
} while (0)

#define STAGE1(ACC, T, S) do {                                                \
    int node_ = base + (T)*16 + w4 + (S);                                     \
    float iv_ = 0.f;                                                          \
    if (node_ < M) {                                                          \
        int dg_ = deg[node_];                                                 \
        iv_ = (dg_ > 0) ? 1.0f / (float)dg_ : 0.f;                            \
    }                                                                         \
    float2 f_ = __half22float2(ACC);                                          \
    aggT[w4 + (S)][lane] = __floats2half2_rn(f_.x * iv_, f_.y * iv_);         \
} while (0)

#define TILE_BODY(T, A0, A1, A2, A3) do {                                     \
    int tile_ = base + (T)*16;                                                \
    STAGE1(A0, T, 0); STAGE1(A1, T, 1); STAGE1(A2, T, 2); STAGE1(A3, T, 3);   \
    int row_ = tile_ + mrow;                                                  \
    int rc_ = (row_ < M) ? row_ : 0;                                          \
    const _Float16* arow_ = Aself + (size_t)rc_ * 128;                        \
    hfrag8 as0_ = *(const hfrag8*)(arow_ + 0 * 32 + quad * 8);                \
    hfrag8 as1_ = *(const hfrag8*)(arow_ + 1 * 32 + quad * 8);                \
    hfrag8 as2_ = *(const hfrag8*)(arow_ + 2 * 32 + quad * 8);                \
    hfrag8 as3_ = *(const hfrag8*)(arow_ + 3 * 32 + quad * 8);                \
    __syncthreads();                                                          \
    f32x4 acc0_ = (f32x4){0.f, 0.f, 0.f, 0.f};                                \
    f32x4 acc1_ = (f32x4){0.f, 0.f, 0.f, 0.f};                                \
    _Pragma("unroll")                                                         \
    for (int ks = 0; ks < 8; ++ks) {                                          \
        hfrag8 af_;                                                           \
        if (ks < 4) af_ = *(const hfrag8*)&aggT[mrow][ks * 16 + quad * 4];    \
        else af_ = (ks == 4) ? as0_ : ((ks == 5) ? as1_ : ((ks == 6) ? as2_ : as3_)); \
        hfrag8 bf0_ = *(const hfrag8*)(Wc + (size_t)(t0 * 16 + mrow) * 256 + ks * 32 + quad * 8); \
        hfrag8 bf1_ = *(const hfrag8*)(Wc + (size_t)(t1 * 16 + mrow) * 256 + ks * 32 + quad * 8); \
        acc0_ = __builtin_amdgcn_mfma_f32_16x16x32_f16(af_, bf0_, acc0_, 0, 0, 0); \
        acc1_ = __builtin_amdgcn_mfma_f32_16x16x32_f16(af_, bf1_, acc1_, 0, 0, 0); \
    }                                                                         \
    _Pragma("unroll")                                                         \
    for (int tt = 0; tt < 2; ++tt) {                                          \
        f32x4 a_ = tt ? acc1_ : acc0_;                                        \
        int col_ = (wave * 2 + tt) * 16 + mrow;                               \
        float bc_ = tt ? bc1 : bc0;                                           \
        _Pragma("unroll")                                                     \
        for (int rr = 0; rr < 4; ++rr) {                                      \
            float v_ = a_[rr] + bc_;                                          \
            if (relu) v_ = fmaxf(v_, 0.f);                                    \
            h2T[quad * 4 + rr][col_] = f2h(v_);                               \
        }                                                                     \
    }                                                                         \
    __syncthreads();                                                          \
    if (outb) {                                                               \
        int rr_ = tid >> 4;                                                   \
        int c8_ = (tid & 15) * 8;                                             \
        int orow_ = tile_ + rr_;                                              \
        if (orow_ < M)                                                        \
            *(uint4*)&outb[(size_t)orow_ * 128 + c8_] = *(const uint4*)&h2T[rr_][c8_]; \
    }                                                                         \
    if (do_lin3 && wave == 0) {                                               \
        f32x4 acc_ = (f32x4){0.f, 0.f, 0.f, 0.f};                             \
        _Pragma("unroll")                                                     \
        for (int ks = 0; ks < 4; ++ks) {                                      \
            hfrag8 af_ = *(const hfrag8*)&h2T[mrow][ks * 32 + quad * 8];      \
            hfrag8 bf_ = *(const hfrag8*)(W3c + (size_t)mrow * 128 + ks * 32 + quad * 8); \
            acc_ = __builtin_amdgcn_mfma_f32_16x16x32_f16(af_, bf_, acc_, 0, 0, 0); \
        }                                                                     \
        int col_ = mrow;                                                      \
        _Pragma("unroll")                                                     \
        for (int rr = 0; rr < 4; ++rr) {                                      \
            int orow_ = tile_ + quad * 4 + rr;                                \
            if (orow_ < M) {                                                  \
                float v_ = acc_[rr];                                          \
                if (col_ < 6) {                                               \
                    zg[(size_t)orow_ * 8 + col_] = f2h(v_);                   \
                } else if (col_ < 12) {                                       \
                    zs[(size_t)orow_ * 6 + (col_ - 6)] = v_ + b3[col_ - 6];   \
                }                                                             \
            }                                                                 \
        }                                                                     \
    }                                                                         \
    __syncthreads();                                                          \
} while (0)

__global__ __launch_bounds__(256, 6) void agg_gemm(
    const __half2* __restrict__ featb,        // [N][64] f16x2 gather table
    const _Float16* __restrict__ Aself,       // [M][128] f16 self rows
    const int* __restrict__ boff,             // [NR*N+1] range-major offsets
    const int* __restrict__ csr,
    const int* __restrict__ deg,              // [N]
    const _Float16* __restrict__ Wc,          // [128][256] f16
    const float* __restrict__ bias,           // [128]
    unsigned short* __restrict__ outb,        // [M][128] f16 (nullable)
    int do_lin3,
    const _Float16* __restrict__ W3c,         // [16][128] f16
    const float* __restrict__ b3,             // [6]
    unsigned short* __restrict__ zg,          // [M][8] f16
    float* __restrict__ zs,                   // [M][6] fp32
    int M, int relu) {
    __shared__ __half2 aggT[16][68];          // 64 + 4 pad (2-way banks = free)
    __shared__ unsigned short h2T[16][136];
    int tid = threadIdx.x;
    int wave = tid >> 6;
    int lane = tid & 63;
    int mrow = lane & 15;
    int quad = lane >> 4;
    int base = blockIdx.x * NPB;
    int w4 = wave * 4;

    // 16 named accumulators: one VGPR each, cannot spill as an array
    __half2 z = __floats2half2_rn(0.f, 0.f);
    __half2 a0 = z, a1 = z, a2 = z, a3 = z, a4 = z, a5 = z, a6 = z, a7 = z;
    __half2 a8 = z, a9 = z, a10 = z, a11 = z, a12 = z, a13 = z, a14 = z, a15 = z;

    // ---- phase 1: src-range-phased gather. Bounds for all 16 wave-nodes of
    // range r arrive via ONE coalesced 32-lane load + shfl broadcast, and the
    // next range's bounds prefetch under the current range's gather.
    int bb_cur = load_bounds(boff, base, w4, lane, M);
#pragma unroll 1
    for (int r = 0; r < NR; ++r) {
        int bb_nxt = (r + 1 < NR)
            ? load_bounds(boff + (size_t)(r + 1) * N_NODES, base, w4, lane, M) : 0;
        GATH4(a0, a1, a2, a3, 0);
        GATH4(a4, a5, a6, a7, 1);
        GATH4(a8, a9, a10, a11, 2);
        GATH4(a12, a13, a14, a15, 3);
        bb_cur = bb_nxt;
    }

    int t0 = wave * 2, t1 = wave * 2 + 1;
    float bc0 = bias[t0 * 16 + mrow];
    float bc1 = bias[t1 * 16 + mrow];

    // ---- phase 2: 4 MFMA tiles of 16 nodes (R17/R19 verbatim)
    TILE_BODY(0, a0, a1, a2, a3);
    TILE_BODY(1, a4, a5, a6, a7);
    TILE_BODY(2, a8, a9, a10, a11);
    TILE_BODY(3, a12, a13, a14, a15);
}

// ------------------------------------------- final: out[n][j] = mean_s zg[s][j] + zs[n][j]
__global__ void out_kernel(const unsigned short* __restrict__ zg,
                           const float* __restrict__ zs,
                           const int* __restrict__ boff,
                           const int* __restrict__ csr,
                           const int* __restrict__ deg,
                           float* __restrict__ out, int M) {
    int idx = blockIdx.x * blockDim.x + threadIdx.x;
    int node = idx >> 3;
    int j = idx & 7;
    if (node >= M || j >= 6) return;
    float acc = 0.f;
#pragma unroll 1
    for (int r = 0; r < NR; ++r) {
        int beg = boff[(size_t)r * N_NODES + node];
        int end = boff[(size_t)r * N_NODES + node + 1];
        for (int i = beg; i < end; ++i) {
            unsigned short u = zg[(size_t)csr[i] * 8 + j];
            acc += __half2float(*(const __half*)&u);
        }
    }
    int dg = deg[node];
    float inv = (dg > 0) ? 1.0f / (float)dg : 0.f;
    out[(size_t)node * 6 + j] = acc * inv + zs[(size_t)node * 6 + j];
}

// ---------------------------------------------------------------- launch
static inline size_t align_up(size_t x, size_t a) { return (x + a - 1) & ~(a - 1); }

extern "C" void kernel_launch(void* const* d_in, const int* in_sizes, int n_in,
                              void* d_out, int out_size, void* d_ws, size_t ws_size,
                              hipStream_t stream) {
    const float* x = (const float*)d_in[0];
    const int* ei = (const int*)d_in[1];
    const float* Wl1 = (const float*)d_in[2];
    const float* Wr1 = (const float*)d_in[3];
    const float* b1 = (const float*)d_in[4];
    const float* Wl2 = (const float*)d_in[5];
    const float* Wr2 = (const float*)d_in[6];
    const float* b2 = (const float*)d_in[7];
    const float* Wl3 = (const float*)d_in[8];
    const float* Wr3 = (const float*)d_in[9];
    const float* b3 = (const float*)d_in[10];

    const int N = in_sizes[0] / 128;   // 100000
    const int E = in_sizes[1] / 2;     // 3200000
    const int* src = ei;
    const int* dst = ei + E;

    // workspace layout
    char* ws = (char*)d_ws;
    size_t off = 0;
    int* cnt = (int*)(ws + off);        off = align_up(off + (size_t)NBINS * 4, 512);
    int* boff = (int*)(ws + off);       off = align_up(off + (size_t)(NBINS + 1) * 4, 512);
    int* block_sums = (int*)(ws + off); off = align_up(off + 512 * 4, 512);
    unsigned int* gcur = (unsigned int*)(ws + off); off = align_up(off + G_PART * 4, 512);
    int* deg = (int*)(ws + off);        off = align_up(off + (size_t)N * 4, 512);
    unsigned short* Wc1 = (unsigned short*)(ws + off); off = align_up(off + 128 * 256 * 2, 512);
    unsigned short* Wc2 = (unsigned short*)(ws + off); off = align_up(off + 128 * 256 * 2, 512);
    unsigned short* W3c = (unsigned short*)(ws + off); off = align_up(off + 16 * 128 * 2, 512);
    int* csr_src = (int*)(ws + off);    off = align_up(off + (size_t)E * 4, 512);
    float* slotA = (float*)(ws + off);  off = align_up(off + (size_t)N * 128 * 4, 512);
    float* slotB = (float*)(ws + off);  off = align_up(off + (size_t)N * 128 * 4, 512);
    uint2* h1b = (uint2*)(ws + off);    off = align_up(off + (size_t)N * 128 * 2, 512);
    // aliases (lifetimes disjoint):
    //  slotA: partial ushort [count..fill] (19.2MB); xb [pack..agg_gemm1] (25.6MB)
    //  slotB: bkt [partition..fill] (14.3MB); zg+zs [agg_gemm2..out] (4MB)
    unsigned short* partial = (unsigned short*)slotA;
    const int cap = 28000;  // per-group mean 25000, +19 sigma
    int* bkt = (int*)slotB;
    uint2* xb = (uint2*)slotA;          // written after fill (partial dead)
    unsigned short* zg = (unsigned short*)slotB;
    float* zs = (float*)((char*)slotB + align_up((size_t)N * 8 * 2, 512));
    (void)ws_size;

    // --- CSR build: radix partition + LDS histogram, (src_range, dst) key
    const int build_grid = G_PART * B_PART;          // 1536 = 6 blocks/CU

    hipMemsetAsync(gcur, 0, G_PART * 4, stream);
    partition_edges<<<A_BLOCKS, 256, 0, stream>>>(src, dst, E, bkt, gcur, cap);
    count_hist<<<build_grid, 256, 0, stream>>>(bkt, gcur, cap, partial);
    scan_partials<<<(NBINS + 255) / 256, 256, 0, stream>>>(partial, cnt);
    deg_kernel<<<(N + 255) / 256, 256, 0, stream>>>(cnt, deg);

    const int nscan = (NBINS + SCHUNK - 1) / SCHUNK;  // 196 <= 256
    scan_blocks<<<nscan, 256, 0, stream>>>(cnt, boff, block_sums, NBINS);
    scan_sums<<<1, 256, 0, stream>>>(block_sums, nscan, boff, NBINS);
    scan_add<<<nscan, 256, 0, stream>>>(boff, block_sums, NBINS);

    fill_hist<<<build_grid, 256, 0, stream>>>(bkt, gcur, cap, partial, boff, csr_src);

    // packs (xb after fill: partial slot is free)
    const int n4 = N * 32;
    pack_f16<<<(n4 + 255) / 256, 256, 0, stream>>>(x, xb, n4);
    pack_weights<<<(65536 + 2048 + 255) / 256, 256, 0, stream>>>(
        Wl1, Wr1, Wl2, Wr2, Wl3, Wr3, Wc1, Wc2, W3c);

    const int aggGrid = (N + NPB - 1) / NPB;   // 1563

    // layer 1: fused gather+GEMM -> h1b (f16)
    agg_gemm<<<aggGrid, 256, 0, stream>>>(
        (const __half2*)xb, (const _Float16*)xb, boff, csr_src, deg,
        (const _Float16*)Wc1, b1, (unsigned short*)h1b,
        0, nullptr, nullptr, nullptr, nullptr, N, 1);
    // layer 2: fused gather+GEMM+lin3 -> zg (f16) + zs (fp32)
    agg_gemm<<<aggGrid, 256, 0, stream>>>(
        (const __half2*)h1b, (const _Float16*)h1b, boff, csr_src, deg,
        (const _Float16*)Wc2, b2, nullptr,
        1, (const _Float16*)W3c, b3, zg, zs, N, 1);
    // final
    out_kernel<<<(N * 8 + 255) / 256, 256, 0, stream>>>(zg, zs, boff, csr_src, deg,
                                                        (float*)d_out, N);
}

// Round 6
// 700.264 us; speedup vs baseline: 2.2391x; 1.1929x over previous
//
#include <hip/hip_runtime.h>
#include <hip/hip_fp16.h>

#define N_NODES 100000
// R21 = R20 (passing) + scalarization & residency:
//  (1) span bounds via readfirstlane -> SGPR: csr chunk loads become s_load
//      (constant cache, off the vector path); routing compares become SALU.
//  (2) NPB 64->48 (3 tiles), grid 2084 ~= 8 blocks/CU, launch_bounds(256,8):
//      attacks the measured 43% occupancy while keeping all blocks co-resident
//      (phasing intact; FETCH must stay ~250MB).
#define G_PART 128
#define NPG 782            // ceil(N/G_PART)
#define NR 8               // src ranges
#define RNG 12500          // nodes per src range (3.2MB f16 slab < 4MB XCD L2)
#define BINS (NPG * NR)    // 6256 bins per dst group
#define BINS_PAD 6272
#define B_PART 12          // blocks per group; grid 1536 = 6 blocks/CU
#define A_BLOCKS 1024
#define NBINS (N_NODES * NR)
#define NPB 48             // nodes per agg_gemm block (3 MFMA tiles); grid 2084

// ---------------------------------------------------------------- CSR build
__global__ __launch_bounds__(256) void partition_edges(
    const int* __restrict__ src, const int* __restrict__ dst, int E,
    int* __restrict__ bkt, unsigned int* __restrict__ gcur, int cap) {
    __shared__ int cnt[G_PART];
    __shared__ unsigned int base[G_PART];
    __shared__ unsigned int cur[G_PART];
    int tid = threadIdx.x;
    if (tid < G_PART) cnt[tid] = 0;
    __syncthreads();
    int per = (E + A_BLOCKS - 1) / A_BLOCKS;
    int beg = blockIdx.x * per;
    int end = min(beg + per, E);
    for (int i = beg + tid; i < end; i += 256) {
        int d = dst[i];
        atomicAdd(&cnt[d / NPG], 1);
    }
    __syncthreads();
    if (tid < G_PART) {
        base[tid] = atomicAdd(&gcur[tid], (unsigned int)cnt[tid]);
        cur[tid] = 0;
    }
    __syncthreads();
    for (int i = beg + tid; i < end; i += 256) {
        int d = dst[i];
        int s = src[i];
        int g = d / NPG;
        unsigned int p = base[g] + atomicAdd(&cur[g], 1u);
        bkt[(size_t)g * cap + p] = ((d - g * NPG) << 17) | s;
    }
}

__global__ __launch_bounds__(256) void count_hist(const int* __restrict__ bkt,
                                                  const unsigned int* __restrict__ gcur,
                                                  int cap,
                                                  unsigned short* __restrict__ partial) {
    __shared__ int hist[BINS_PAD];
    int g = blockIdx.x & (G_PART - 1);
    int b = blockIdx.x / G_PART;
    int tid = threadIdx.x;
    for (int i = tid; i < BINS; i += 256) hist[i] = 0;
    __syncthreads();
    int len = (int)gcur[g];
    int per = (len + B_PART - 1) / B_PART;
    int ibeg = b * per;
    int iend = min(ibeg + per, len);
    const int* bp = bkt + (size_t)g * cap;
    for (int i = ibeg + tid; i < iend; i += 256) {
        int v = __builtin_nontemporal_load(bp + i);
        int bin = ((v & 0x1FFFF) / RNG) * NPG + (v >> 17);  // (src_range, local_dst)
        atomicAdd(&hist[bin], 1);
    }
    __syncthreads();
    size_t basep = (size_t)(g * B_PART + b) * BINS;
    for (int j = tid; j < BINS; j += 256) partial[basep + j] = (unsigned short)hist[j];
}

// global bin order is RANGE-MAJOR: B = r*N + dst  (csr is range-major)
__global__ __launch_bounds__(256) void scan_partials(unsigned short* __restrict__ partial,
                                                     int* __restrict__ cnt) {
    int B = blockIdx.x * 256 + threadIdx.x;
    if (B >= NBINS) return;
    int r = B / N_NODES;
    int dstn = B - r * N_NODES;
    int g = dstn / NPG;
    int i = r * NPG + (dstn - g * NPG);
    size_t basep = (size_t)g * B_PART * BINS + i;
    int run = 0;
#pragma unroll 4
    for (int b = 0; b < B_PART; ++b) {
        size_t idx = basep + (size_t)b * BINS;
        int t = partial[idx];
        partial[idx] = (unsigned short)run;
        run += t;
    }
    cnt[B] = run;
}

__global__ __launch_bounds__(256) void deg_kernel(const int* __restrict__ cnt,
                                                  int* __restrict__ deg) {
    int n = blockIdx.x * 256 + threadIdx.x;
    if (n >= N_NODES) return;
    int s = 0;
#pragma unroll
    for (int r = 0; r < NR; ++r) s += cnt[(size_t)r * N_NODES + n];
    deg[n] = s;
}

// ---------------- grid-parallel exclusive scan over NBINS
#define SCHUNK 4096

__global__ __launch_bounds__(256) void scan_blocks(const int* __restrict__ cnt,
                                                   int* __restrict__ boff,
                                                   int* __restrict__ block_sums, int n) {
    __shared__ int ts[256];
    int tid = threadIdx.x;
    int base = blockIdx.x * SCHUNK + tid * 16;
    int v[16];
    int s = 0;
#pragma unroll
    for (int j = 0; j < 16; ++j) {
        int i = base + j;
        v[j] = (i < n) ? cnt[i] : 0;
        s += v[j];
    }
    ts[tid] = s;
    __syncthreads();
    for (int off = 1; off < 256; off <<= 1) {
        int t = 0;
        if (tid >= off) t = ts[tid - off];
        __syncthreads();
        if (tid >= off) ts[tid] += t;
        __syncthreads();
    }
    int run = (tid > 0) ? ts[tid - 1] : 0;
    if (tid == 255) block_sums[blockIdx.x] = ts[255];
#pragma unroll
    for (int j = 0; j < 16; ++j) {
        int i = base + j;
        if (i < n) boff[i] = run;
        run += v[j];
    }
}

__global__ __launch_bounds__(256) void scan_sums(int* __restrict__ block_sums, int nb,
                                                 int* __restrict__ boff, int n) {
    __shared__ int ts[256];
    int tid = threadIdx.x;
    int v = (tid < nb) ? block_sums[tid] : 0;
    ts[tid] = v;
    __syncthreads();
    for (int off = 1; off < 256; off <<= 1) {
        int t = 0;
        if (tid >= off) t = ts[tid - off];
        __syncthreads();
        if (tid >= off) ts[tid] += t;
        __syncthreads();
    }
    if (tid < nb) block_sums[tid] = (tid > 0) ? ts[tid - 1] : 0;
    if (tid == 255) boff[n] = ts[255];
}

__global__ __launch_bounds__(256) void scan_add(int* __restrict__ boff,
                                                const int* __restrict__ block_sums, int n) {
    int tid = threadIdx.x;
    int off = block_sums[blockIdx.x];
    int base = blockIdx.x * SCHUNK + tid * 16;
#pragma unroll
    for (int j = 0; j < 16; ++j) {
        int i = base + j;
        if (i < n) boff[i] += off;
    }
}

__global__ __launch_bounds__(256) void fill_hist(const int* __restrict__ bkt,
                                                 const unsigned int* __restrict__ gcur,
                                                 int cap,
                                                 const unsigned short* __restrict__ partial,
                                                 const int* __restrict__ boff,
                                                 int* __restrict__ csr_src) {
    __shared__ int cur[BINS_PAD];
    int g = blockIdx.x & (G_PART - 1);
    int b = blockIdx.x / G_PART;
    int tid = threadIdx.x;
    size_t pbase = (size_t)(g * B_PART + b) * BINS;
    for (int i = tid; i < BINS; i += 256) {
        int r = i / NPG;
        int dstn = g * NPG + (i - r * NPG);
        if (dstn < N_NODES)
            cur[i] = boff[(size_t)r * N_NODES + dstn] + (int)partial[pbase + i];
    }
    __syncthreads();
    int len = (int)gcur[g];
    int per = (len + B_PART - 1) / B_PART;
    int ibeg = b * per;
    int iend = min(ibeg + per, len);
    const int* bp = bkt + (size_t)g * cap;
    for (int i = ibeg + tid; i < iend; i += 256) {
        int v = __builtin_nontemporal_load(bp + i);
        int bin = ((v & 0x1FFFF) / RNG) * NPG + (v >> 17);
        int p = atomicAdd(&cur[bin], 1);
        csr_src[p] = v & 0x1FFFF;
    }
}

// ---------------------------------------------------------------- f16 packs
__global__ __launch_bounds__(256) void pack_f16(const float* __restrict__ in,
                                                uint2* __restrict__ out, int n4) {
    int i = blockIdx.x * 256 + threadIdx.x;
    if (i >= n4) return;
    float4 v = *(const float4*)&in[(size_t)i * 4];
    __half2 p0 = __floats2half2_rn(v.x, v.y);
    __half2 p1 = __floats2half2_rn(v.z, v.w);
    uint2 o;
    o.x = *(const uint*)&p0;
    o.y = *(const uint*)&p1;
    out[i] = o;
}

static __device__ inline unsigned short f2h(float v) {
    __half h = __float2half(v);
    return *(const unsigned short*)&h;
}

__global__ __launch_bounds__(256) void pack_weights(
    const float* __restrict__ Wl1, const float* __restrict__ Wr1,
    const float* __restrict__ Wl2, const float* __restrict__ Wr2,
    const float* __restrict__ Wl3, const float* __restrict__ Wr3,
    unsigned short* __restrict__ Wc1, unsigned short* __restrict__ Wc2,
    unsigned short* __restrict__ W3c) {
    int idx = blockIdx.x * 256 + threadIdx.x;
    if (idx < 32768) {
        int n = idx >> 8, k = idx & 255;
        Wc1[idx] = f2h((k < 128) ? Wl1[n * 128 + k] : Wr1[n * 128 + (k - 128)]);
    } else if (idx < 65536) {
        int t = idx - 32768;
        int n = t >> 8, k = t & 255;
        Wc2[t] = f2h((k < 128) ? Wl2[n * 128 + k] : Wr2[n * 128 + (k - 128)]);
    } else if (idx < 65536 + 2048) {
        int t = idx - 65536;
        int n = t >> 7, k = t & 127;
        float v = (n < 6) ? Wl3[n * 128 + k] : ((n < 12) ? Wr3[(n - 6) * 128 + k] : 0.f);
        W3c[t] = f2h(v);
    }
}

// --------------------------------------------- fused agg + MFMA GEMM (+lin3)
typedef __attribute__((ext_vector_type(8))) _Float16 hfrag8;
typedef __attribute__((ext_vector_type(4))) float f32x4;

// per-range bound fetch: lane 2k -> begin of wave-node k, lane 2k+1 -> end
// (= begin of node k+1; boff is contiguous over nodes within a range).
// 12 nodes/wave -> lanes 0..23.
static __device__ inline int load_bounds(const int* __restrict__ boff_r,
                                         int base, int w4, int lane, int M) {
    int bb = 0;
    if (lane < 48) {
        int k = lane >> 1;
        int node = base + (k >> 2) * 16 + w4 + (k & 3) + (lane & 1);
        if (node > M) node = M;
        bb = boff_r[node];
    }
    return bb;
}

// span-fused gather for group T (4 contiguous nodes). Bounds scalarized via
// readfirstlane: csr loads -> s_load (K$), routing compares -> SALU, loop
// control scalar. Vector pipe carries only featb loads + v_pk_add_f16.
#define GATH4(A0, A1, A2, A3, T) do {                                         \
    int k8_ = (T) * 8;                                                        \
    int B_  = __builtin_amdgcn_readfirstlane(__shfl(bb_cur, k8_ + 0));        \
    int e0_ = __builtin_amdgcn_readfirstlane(__shfl(bb_cur, k8_ + 1));        \
    int e1_ = __builtin_amdgcn_readfirstlane(__shfl(bb_cur, k8_ + 3));        \
    int e2_ = __builtin_amdgcn_readfirstlane(__shfl(bb_cur, k8_ + 5));        \
    int E_  = __builtin_amdgcn_readfirstlane(__shfl(bb_cur, k8_ + 7));        \
    for (int i_ = B_; i_ < E_; i_ += 8) {                                     \
        int c_[8];                                                            \
        _Pragma("unroll")                                                     \
        for (int j = 0; j < 8; ++j) {                                         \
            int idx_ = i_ + j;                                                \
            if (idx_ > E_ - 1) idx_ = E_ - 1;                                 \
            c_[j] = csr[idx_];                                                \
        }                                                                     \
        __half2 f_[8];                                                        \
        _Pragma("unroll")                                                     \
        for (int j = 0; j < 8; ++j)                                           \
            f_[j] = featb[(uint)c_[j] * 64u + lane];                          \
        _Pragma("unroll")                                                     \
        for (int j = 0; j < 8; ++j) {                                         \
            int gi_ = i_ + j;                                                 \
            if (gi_ < E_) {                                                   \
                __half2 v_ = f_[j];                                           \
                if (gi_ < e0_)      A0 = __hadd2(A0, v_);                     \
                else if (gi_ < e1_) A1 = __hadd2(A1, v_);                     \
                else if (gi_ < e2_) A2 = __hadd2(A2, v_);                     \
                else                A3 = __hadd2(A3, v_);                     \
            }                                                                 \
        }                                                                     \
    }                                                                         \
} while (0)

#define STAGE1(ACC, T, S) do {                                                \
    int node_ = base + (T)*16 + w4 + (S);                                     \
    float iv_ = 0.f;                                                          \
    if (node_ < M) {                                                          \
        int dg_ = deg[node_];                                                 \
        iv_ = (dg_ > 0) ? 1.0f / (float)dg_ : 0.f;                            \
    }                                                                         \
    float2 f_ = __half22float2(ACC);                                          \
    aggT[w4 + (S)][lane] = __floats2half2_rn(f_.x * iv_, f_.y * iv_);         \
} while (0)

#define TILE_BODY(T, A0, A1, A2, A3) do {                                     \
    int tile_ = base + (T)*16;                                                \
    STAGE1(A0, T, 0); STAGE1(A1, T, 1); STAGE1(A2, T, 2); STAGE1(A3, T, 3);   \
    int row_ = tile_ + mrow;                                                  \
    int rc_ = (row_ < M) ? row_ : 0;                                          \
    const _Float16* arow_ = Aself + (size_t)rc_ * 128;                        \
    hfrag8 as0_ = *(const hfrag8*)(arow_ + 0 * 32 + quad * 8);                \
    hfrag8 as1_ = *(const hfrag8*)(arow_ + 1 * 32 + quad * 8);                \
    hfrag8 as2_ = *(const hfrag8*)(arow_ + 2 * 32 + quad * 8);                \
    hfrag8 as3_ = *(const hfrag8*)(arow_ + 3 * 32 + quad * 8);                \
    __syncthreads();                                                          \
    f32x4 acc0_ = (f32x4){0.f, 0.f, 0.f, 0.f};                                \
    f32x4 acc1_ = (f32x4){0.f, 0.f, 0.f, 0.f};                                \
    _Pragma("unroll")                                                         \
    for (int ks = 0; ks < 8; ++ks) {                                          \
        hfrag8 af_;                                                           \
        if (ks < 4) af_ = *(const hfrag8*)&aggT[mrow][ks * 16 + quad * 4];    \
        else af_ = (ks == 4) ? as0_ : ((ks == 5) ? as1_ : ((ks == 6) ? as2_ : as3_)); \
        hfrag8 bf0_ = *(const hfrag8*)(Wc + (size_t)(t0 * 16 + mrow) * 256 + ks * 32 + quad * 8); \
        hfrag8 bf1_ = *(const hfrag8*)(Wc + (size_t)(t1 * 16 + mrow) * 256 + ks * 32 + quad * 8); \
        acc0_ = __builtin_amdgcn_mfma_f32_16x16x32_f16(af_, bf0_, acc0_, 0, 0, 0); \
        acc1_ = __builtin_amdgcn_mfma_f32_16x16x32_f16(af_, bf1_, acc1_, 0, 0, 0); \
    }                                                                         \
    _Pragma("unroll")                                                         \
    for (int tt = 0; tt < 2; ++tt) {                                          \
        f32x4 a_ = tt ? acc1_ : acc0_;                                        \
        int col_ = (wave * 2 + tt) * 16 + mrow;                               \
        float bc_ = tt ? bc1 : bc0;                                           \
        _Pragma("unroll")                                                     \
        for (int rr = 0; rr < 4; ++rr) {                                      \
            float v_ = a_[rr] + bc_;                                          \
            if (relu) v_ = fmaxf(v_, 0.f);                                    \
            h2T[quad * 4 + rr][col_] = f2h(v_);                               \
        }                                                                     \
    }                                                                         \
    __syncthreads();                                                          \
    if (outb) {                                                               \
        int rr_ = tid >> 4;                                                   \
        int c8_ = (tid & 15) * 8;                                             \
        int orow_ = tile_ + rr_;                                              \
        if (orow_ < M)                                                        \
            *(uint4*)&outb[(size_t)orow_ * 128 + c8_] = *(const uint4*)&h2T[rr_][c8_]; \
    }                                                                         \
    if (do_lin3 && wave == 0) {                                               \
        f32x4 acc_ = (f32x4){0.f, 0.f, 0.f, 0.f};                             \
        _Pragma("unroll")                                                     \
        for (int ks = 0; ks < 4; ++ks) {                                      \
            hfrag8 af_ = *(const hfrag8*)&h2T[mrow][ks * 32 + quad * 8];      \
            hfrag8 bf_ = *(const hfrag8*)(W3c + (size_t)mrow * 128 + ks * 32 + quad * 8); \
            acc_ = __builtin_amdgcn_mfma_f32_16x16x32_f16(af_, bf_, acc_, 0, 0, 0); \
        }                                                                     \
        int col_ = mrow;                                                      \
        _Pragma("unroll")                                                     \
        for (int rr = 0; rr < 4; ++rr) {                                      \
            int orow_ = tile_ + quad * 4 + rr;                                \
            if (orow_ < M) {                                                  \
                float v_ = acc_[rr];                                          \
                if (col_ < 6) {                                               \
                    zg[(size_t)orow_ * 8 + col_] = f2h(v_);                   \
                } else if (col_ < 12) {                                       \
                    zs[(size_t)orow_ * 6 + (col_ - 6)] = v_ + b3[col_ - 6];   \
                }                                                             \
            }                                                                 \
        }                                                                     \
    }                                                                         \
    __syncthreads();                                                          \
} while (0)

__global__ __launch_bounds__(256, 8) void agg_gemm(
    const __half2* __restrict__ featb,        // [N][64] f16x2 gather table
    const _Float16* __restrict__ Aself,       // [M][128] f16 self rows
    const int* __restrict__ boff,             // [NR*N+1] range-major offsets
    const int* __restrict__ csr,
    const int* __restrict__ deg,              // [N]
    const _Float16* __restrict__ Wc,          // [128][256] f16
    const float* __restrict__ bias,           // [128]
    unsigned short* __restrict__ outb,        // [M][128] f16 (nullable)
    int do_lin3,
    const _Float16* __restrict__ W3c,         // [16][128] f16
    const float* __restrict__ b3,             // [6]
    unsigned short* __restrict__ zg,          // [M][8] f16
    float* __restrict__ zs,                   // [M][6] fp32
    int M, int relu) {
    __shared__ __half2 aggT[16][68];          // 64 + 4 pad (2-way banks = free)
    __shared__ unsigned short h2T[16][136];
    int tid = threadIdx.x;
    int wave = tid >> 6;
    int lane = tid & 63;
    int mrow = lane & 15;
    int quad = lane >> 4;
    int base = blockIdx.x * NPB;
    int w4 = wave * 4;

    // 12 named accumulators: one VGPR each, cannot spill as an array
    __half2 z = __floats2half2_rn(0.f, 0.f);
    __half2 a0 = z, a1 = z, a2 = z, a3 = z, a4 = z, a5 = z;
    __half2 a6 = z, a7 = z, a8 = z, a9 = z, a10 = z, a11 = z;

    // ---- phase 1: src-range-phased gather. Bounds for all 12 wave-nodes of
    // range r arrive via ONE coalesced load + shfl broadcast; next range's
    // bounds prefetch under the current range's gather.
    int bb_cur = load_bounds(boff, base, w4, lane, M);
#pragma unroll 1
    for (int r = 0; r < NR; ++r) {
        int bb_nxt = (r + 1 < NR)
            ? load_bounds(boff + (size_t)(r + 1) * N_NODES, base, w4, lane, M) : 0;
        GATH4(a0, a1, a2, a3, 0);
        GATH4(a4, a5, a6, a7, 1);
        GATH4(a8, a9, a10, a11, 2);
        bb_cur = bb_nxt;
    }

    int t0 = wave * 2, t1 = wave * 2 + 1;
    float bc0 = bias[t0 * 16 + mrow];
    float bc1 = bias[t1 * 16 + mrow];

    // ---- phase 2: 3 MFMA tiles of 16 nodes (structure R17/R19/R20 verbatim)
    TILE_BODY(0, a0, a1, a2, a3);
    TILE_BODY(1, a4, a5, a6, a7);
    TILE_BODY(2, a8, a9, a10, a11);
}

// ------------------------------------------- final: out[n][j] = mean_s zg[s][j] + zs[n][j]
__global__ void out_kernel(const unsigned short* __restrict__ zg,
                           const float* __restrict__ zs,
                           const int* __restrict__ boff,
                           const int* __restrict__ csr,
                           const int* __restrict__ deg,
                           float* __restrict__ out, int M) {
    int idx = blockIdx.x * blockDim.x + threadIdx.x;
    int node = idx >> 3;
    int j = idx & 7;
    if (node >= M || j >= 6) return;
    float acc = 0.f;
#pragma unroll 1
    for (int r = 0; r < NR; ++r) {
        int beg = boff[(size_t)r * N_NODES + node];
        int end = boff[(size_t)r * N_NODES + node + 1];
        for (int i = beg; i < end; ++i) {
            unsigned short u = zg[(size_t)csr[i] * 8 + j];
            acc += __half2float(*(const __half*)&u);
        }
    }
    int dg = deg[node];
    float inv = (dg > 0) ? 1.0f / (float)dg : 0.f;
    out[(size_t)node * 6 + j] = acc * inv + zs[(size_t)node * 6 + j];
}

// ---------------------------------------------------------------- launch
static inline size_t align_up(size_t x, size_t a) { return (x + a - 1) & ~(a - 1); }

extern "C" void kernel_launch(void* const* d_in, const int* in_sizes, int n_in,
                              void* d_out, int out_size, void* d_ws, size_t ws_size,
                              hipStream_t stream) {
    const float* x = (const float*)d_in[0];
    const int* ei = (const int*)d_in[1];
    const float* Wl1 = (const float*)d_in[2];
    const float* Wr1 = (const float*)d_in[3];
    const float* b1 = (const float*)d_in[4];
    const float* Wl2 = (const float*)d_in[5];
    const float* Wr2 = (const float*)d_in[6];
    const float* b2 = (const float*)d_in[7];
    const float* Wl3 = (const float*)d_in[8];
    const float* Wr3 = (const float*)d_in[9];
    const float* b3 = (const float*)d_in[10];

    const int N = in_sizes[0] / 128;   // 100000
    const int E = in_sizes[1] / 2;     // 3200000
    const int* src = ei;
    const int* dst = ei + E;

    // workspace layout
    char* ws = (char*)d_ws;
    size_t off = 0;
    int* cnt = (int*)(ws + off);        off = align_up(off + (size_t)NBINS * 4, 512);
    int* boff = (int*)(ws + off);       off = align_up(off + (size_t)(NBINS + 1) * 4, 512);
    int* block_sums = (int*)(ws + off); off = align_up(off + 512 * 4, 512);
    unsigned int* gcur = (unsigned int*)(ws + off); off = align_up(off + G_PART * 4, 512);
    int* deg = (int*)(ws + off);        off = align_up(off + (size_t)N * 4, 512);
    unsigned short* Wc1 = (unsigned short*)(ws + off); off = align_up(off + 128 * 256 * 2, 512);
    unsigned short* Wc2 = (unsigned short*)(ws + off); off = align_up(off + 128 * 256 * 2, 512);
    unsigned short* W3c = (unsigned short*)(ws + off); off = align_up(off + 16 * 128 * 2, 512);
    int* csr_src = (int*)(ws + off);    off = align_up(off + (size_t)E * 4, 512);
    float* slotA = (float*)(ws + off);  off = align_up(off + (size_t)N * 128 * 4, 512);
    float* slotB = (float*)(ws + off);  off = align_up(off + (size_t)N * 128 * 4, 512);
    uint2* h1b = (uint2*)(ws + off);    off = align_up(off + (size_t)N * 128 * 2, 512);
    // aliases (lifetimes disjoint):
    //  slotA: partial ushort [count..fill] (19.2MB); xb [pack..agg_gemm1] (25.6MB)
    //  slotB: bkt [partition..fill] (14.3MB); zg+zs [agg_gemm2..out] (4MB)
    unsigned short* partial = (unsigned short*)slotA;
    const int cap = 28000;  // per-group mean 25000, +19 sigma
    int* bkt = (int*)slotB;
    uint2* xb = (uint2*)slotA;          // written after fill (partial dead)
    unsigned short* zg = (unsigned short*)slotB;
    float* zs = (float*)((char*)slotB + align_up((size_t)N * 8 * 2, 512));
    (void)ws_size;

    // --- CSR build: radix partition + LDS histogram, (src_range, dst) key
    const int build_grid = G_PART * B_PART;          // 1536 = 6 blocks/CU

    hipMemsetAsync(gcur, 0, G_PART * 4, stream);
    partition_edges<<<A_BLOCKS, 256, 0, stream>>>(src, dst, E, bkt, gcur, cap);
    count_hist<<<build_grid, 256, 0, stream>>>(bkt, gcur, cap, partial);
    scan_partials<<<(NBINS + 255) / 256, 256, 0, stream>>>(partial, cnt);
    deg_kernel<<<(N + 255) / 256, 256, 0, stream>>>(cnt, deg);

    const int nscan = (NBINS + SCHUNK - 1) / SCHUNK;  // 196 <= 256
    scan_blocks<<<nscan, 256, 0, stream>>>(cnt, boff, block_sums, NBINS);
    scan_sums<<<1, 256, 0, stream>>>(block_sums, nscan, boff, NBINS);
    scan_add<<<nscan, 256, 0, stream>>>(boff, block_sums, NBINS);

    fill_hist<<<build_grid, 256, 0, stream>>>(bkt, gcur, cap, partial, boff, csr_src);

    // packs (xb after fill: partial slot is free)
    const int n4 = N * 32;
    pack_f16<<<(n4 + 255) / 256, 256, 0, stream>>>(x, xb, n4);
    pack_weights<<<(65536 + 2048 + 255) / 256, 256, 0, stream>>>(
        Wl1, Wr1, Wl2, Wr2, Wl3, Wr3, Wc1, Wc2, W3c);

    const int aggGrid = (N + NPB - 1) / NPB;   // 2084 ~= 8 blocks/CU

    // layer 1: fused gather+GEMM -> h1b (f16)
    agg_gemm<<<aggGrid, 256, 0, stream>>>(
        (const __half2*)xb, (const _Float16*)xb, boff, csr_src, deg,
        (const _Float16*)Wc1, b1, (unsigned short*)h1b,
        0, nullptr, nullptr, nullptr, nullptr, N, 1);
    // layer 2: fused gather+GEMM+lin3 -> zg (f16) + zs (fp32)
    agg_gemm<<<aggGrid, 256, 0, stream>>>(
        (const __half2*)h1b, (const _Float16*)h1b, boff, csr_src, deg,
        (const _Float16*)Wc2, b2, nullptr,
        1, (const _Float16*)W3c, b3, zg, zs, N, 1);
    // final
    out_kernel<<<(N * 8 + 255) / 256, 256, 0, stream>>>(zg, zs, boff, csr_src, deg,
                                                        (float*)d_out, N);
}